// Round 4
// baseline (1440.261 us; speedup 1.0000x reference)
//
#include <hip/hip_runtime.h>
#include <hip/hip_fp16.h>

#define N_NODES 50000
#define N_FEAT  128
#define HID     64
#define N_EDGES 800000
#define N_GRAPHS 64
#define MAXDEG  64
#define BN_EPS  1e-5f
#define NB256(n) (((n) + 255) / 256)

// ---------------- zero fill counters ----------------
__global__ __launch_bounds__(256) void k_zero(int* fill) {
    int i = blockIdx.x * 256 + threadIdx.x;
    if (i < N_NODES) fill[i] = 0;
}

// ---------------- fused dual-GEMM with piggybacked edge placement ----------------
// 2500 blocks x 20 nodes: stage x ONCE, compute BOTH x@W_in^T (fp32 h) and
// x@W1^T (fp16 g16). W chunks are software-pipelined through registers so the
// L2 load latency of chunk c+1 hides under the compute of chunk c.
#define GE_NB 2500
__global__ __launch_bounds__(256) void k_gemmedge(const int* __restrict__ ei,
                                                  int* fill, unsigned short* __restrict__ colp,
                                                  const float* __restrict__ x,
                                                  const float* __restrict__ W_in,
                                                  const float* __restrict__ W1,
                                                  float* __restrict__ h,
                                                  __half* __restrict__ g16) {
    __shared__ float4 Wt[2][8 * 65];   // 8 k4-slices of both W, stride 65 (conflict-free)
    __shared__ float4 xs[20 * 32];     // 20 node rows of x
    const int bid = blockIdx.x;
    const int t = threadIdx.x;

    // edge slice: issue atomics now, consume results after the GEMM
    const int ebase = bid * 320;
    int s1 = ei[ebase + t];
    int d1 = ei[N_EDGES + ebase + t];
    int k1 = atomicAdd(&fill[d1], 1);
    int s2 = 0, d2 = 0, k2 = MAXDEG;
    if (t < 64) {
        s2 = ei[ebase + 256 + t];
        d2 = ei[N_EDGES + ebase + 256 + t];
        k2 = atomicAdd(&fill[d2], 1);
    }

    // W chunk 0 prefetch into registers (each thread owns 2 slots of each W)
    const float4* W0v = (const float4*)W_in;
    const float4* W1v = (const float4*)W1;
    const int h2a = t >> 3, k4a = t & 7;
    const int h2b = h2a + 32;                 // second slot: i = t + 256
    float4 w0a = W0v[h2a * 32 + k4a];
    float4 w1a = W1v[h2a * 32 + k4a];
    float4 w0b = W0v[h2b * 32 + k4a];
    float4 w1b = W1v[h2b * 32 + k4a];

    const int base = bid * 20;
    const float4* xv = (const float4*)(x + (long long)base * N_FEAT);
    for (int i = t; i < 20 * 32; i += 256) xs[i] = xv[i];

    const int hh = t & 63;
    const int ng = t >> 6;
    float4 a0[5], a1[5];
#pragma unroll
    for (int j = 0; j < 5; ++j) {
        a0[j] = make_float4(0.f, 0.f, 0.f, 0.f);
        a1[j] = make_float4(0.f, 0.f, 0.f, 0.f);
    }

    for (int c = 0; c < 32; c += 8) {
        __syncthreads();  // WAR on Wt (also orders xs staging before first MAC)
        Wt[0][k4a * 65 + h2a] = w0a;  Wt[1][k4a * 65 + h2a] = w1a;
        Wt[0][k4a * 65 + h2b] = w0b;  Wt[1][k4a * 65 + h2b] = w1b;
        if (c + 8 < 32) {   // prefetch next chunk; latency hides under compute
            w0a = W0v[h2a * 32 + c + 8 + k4a]; w1a = W1v[h2a * 32 + c + 8 + k4a];
            w0b = W0v[h2b * 32 + c + 8 + k4a]; w1b = W1v[h2b * 32 + c + 8 + k4a];
        }
        __syncthreads();
#pragma unroll
        for (int k4 = 0; k4 < 8; ++k4) {
            float4 w0 = Wt[0][k4 * 65 + hh];
            float4 w1 = Wt[1][k4 * 65 + hh];
#pragma unroll
            for (int j = 0; j < 5; ++j) {
                float4 xx = xs[(ng + 4 * j) * 32 + c + k4];   // wave-broadcast
                a0[j].x += w0.x * xx.x; a0[j].y += w0.y * xx.y;
                a0[j].z += w0.z * xx.z; a0[j].w += w0.w * xx.w;
                a1[j].x += w1.x * xx.x; a1[j].y += w1.y * xx.y;
                a1[j].z += w1.z * xx.z; a1[j].w += w1.w * xx.w;
            }
        }
    }
#pragma unroll
    for (int j = 0; j < 5; ++j) {
        int node = base + ng + 4 * j;
        h[node * HID + hh]   = a0[j].x + a0[j].y + a0[j].z + a0[j].w;
        g16[node * HID + hh] = __float2half(a1[j].x + a1[j].y + a1[j].z + a1[j].w);
    }

    // deferred stores: atomic results long since returned
    if (k1 < MAXDEG) colp[d1 * MAXDEG + k1] = (unsigned short)s1;
    if (k2 < MAXDEG) colp[d2 * MAXDEG + k2] = (unsigned short)s2;
}

// ---- fp16 row accumulate, scaled (FMA — same cost as plain add) ----
__device__ __forceinline__ void acc8s(const uint4 r, float* a, float s) {
    float2 f0 = __half22float2(*(const __half2*)&r.x);
    float2 f1 = __half22float2(*(const __half2*)&r.y);
    float2 f2 = __half22float2(*(const __half2*)&r.z);
    float2 f3 = __half22float2(*(const __half2*)&r.w);
    a[0] += s * f0.x; a[1] += s * f0.y; a[2] += s * f1.x; a[3] += s * f1.y;
    a[4] += s * f2.x; a[5] += s * f2.y; a[6] += s * f3.x; a[7] += s * f3.y;
}

// ------ fused gather(+BN/ReLU/res) [+ per-wave GEMM], ONE node per 8-lane sub ------
// 1563 blocks x 32 nodes. Each lane owns one feature-octet of its sub's node.
// VGPR diet vs R3 (which spilled at 256 VGPR): BN folded to SC/SH (16 regs,
// precomputed), scalar GEMM accumulators (8 regs), __launch_bounds__(256,4)
// pins the allocator at <=128 VGPR -> 4 blocks/CU.
template <bool NSCALE, bool DOGEMM>
__global__ __launch_bounds__(256, 4) void k_gather_fused(const __half* __restrict__ gin,
                                                      const unsigned short* __restrict__ colp,
                                                      const int* __restrict__ fill,
                                                      const float* __restrict__ b,
                                                      const float* __restrict__ gamma,
                                                      const float* __restrict__ beta,
                                                      const float* __restrict__ mean,
                                                      const float* __restrict__ var,
                                                      const float4* __restrict__ res4,
                                                      float4* __restrict__ h4,
                                                      const float* __restrict__ W,
                                                      __half* __restrict__ gout) {
    __shared__ float4 Wt[DOGEMM ? 16 * 65 : 1];
    __shared__ float4 hrow[DOGEMM ? 32 * 17 : 1];   // stride 17

    const int t = threadIdx.x;
    const int wv = t >> 6;
    const int lane = t & 63;
    const int hh8 = lane & 7;       // feature octet
    const int sub = lane >> 3;      // node slot within wave
    const int nl = wv * 8 + sub;    // local node 0..31
    const int n = blockIdx.x * 32 + nl;
    const bool nvalid = (n < N_NODES);

    if (DOGEMM) {
        const float4* Wv = (const float4*)W;
        for (int i = t; i < HID * 16; i += 256) {
            int h2 = i >> 4, k4 = i & 15;
            Wt[k4 * 65 + h2] = Wv[i];
        }
        __syncthreads();   // only block barrier: Wt visible before any use
    }

    // BN fold: o = a*di*SC + SH, SC = g*rsqrt(v+eps), SH = (b-m)*SC + e.
    // Param arrays die here; only 16 regs (SC,SH) live across the gather loop.
    float SC[8], SH[8];
    {
        float4 b0 = ((const float4*)b)[hh8 * 2],     b1 = ((const float4*)b)[hh8 * 2 + 1];
        float4 g0 = ((const float4*)gamma)[hh8 * 2], g1 = ((const float4*)gamma)[hh8 * 2 + 1];
        float4 e0 = ((const float4*)beta)[hh8 * 2],  e1 = ((const float4*)beta)[hh8 * 2 + 1];
        float4 m0 = ((const float4*)mean)[hh8 * 2],  m1 = ((const float4*)mean)[hh8 * 2 + 1];
        float4 v0 = ((const float4*)var)[hh8 * 2],   v1 = ((const float4*)var)[hh8 * 2 + 1];
        float bb[8] = {b0.x, b0.y, b0.z, b0.w, b1.x, b1.y, b1.z, b1.w};
        float gg[8] = {g0.x, g0.y, g0.z, g0.w, g1.x, g1.y, g1.z, g1.w};
        float ee[8] = {e0.x, e0.y, e0.z, e0.w, e1.x, e1.y, e1.z, e1.w};
        float mm[8] = {m0.x, m0.y, m0.z, m0.w, m1.x, m1.y, m1.z, m1.w};
        float vv[8] = {v0.x, v0.y, v0.z, v0.w, v1.x, v1.y, v1.z, v1.w};
#pragma unroll
        for (int i = 0; i < 8; ++i) {
            SC[i] = gg[i] * rsqrtf(vv[i] + BN_EPS);
            SH[i] = (bb[i] - mm[i]) * SC[i] + ee[i];
        }
    }

    const uint4* gv = (const uint4*)gin;  // row = 8 x uint4 (128 B)
    const int fl = nvalid ? fill[n] : 0;
    const int deg = fl < MAXDEG ? fl : MAXDEG;

    float a[8];
#pragma unroll
    for (int i = 0; i < 8; ++i) a[i] = 0.f;

    const unsigned long long* cp4 =
        (const unsigned long long*)(colp + (size_t)n * MAXDEG);  // deref only if deg>0

    for (int rb = 0; rb < MAXDEG; rb += 4) {
        if (!__any(rb < deg)) break;          // wave-uniform exit
        if (rb < deg) {                       // sub-uniform mask (8 lanes alike)
            unsigned long long cc = cp4[rb >> 2];   // 4 packed cols, broadcast
            int c[4]; float s[4]; uint4 v[4];
#pragma unroll
            for (int k = 0; k < 4; ++k) {
                bool pk = (rb + k) < deg;
                c[k] = pk ? (int)((cc >> (16 * k)) & 0xFFFFull) : 0;
                if (NSCALE) s[k] = pk ? rsqrtf((float)fill[c[k]] + 1.0f) : 0.0f;
                else        s[k] = pk ? 1.0f : 0.0f;
            }
#pragma unroll
            for (int k = 0; k < 4; ++k) v[k] = gv[(size_t)c[k] * 8 + hh8];
#pragma unroll
            for (int k = 0; k < 4; ++k) acc8s(v[k], a, s[k]);
        }
    }

    const float di = rsqrtf((float)fl + 1.0f);
    if (nvalid) acc8s(gv[(size_t)n * 8 + hh8], a, NSCALE ? di : 1.0f);  // self loop

    float o[8];
#pragma unroll
    for (int i = 0; i < 8; ++i)
        o[i] = fmaxf(fmaf(a[i] * di, SC[i], SH[i]), 0.f);

    if (res4 != nullptr && nvalid) {
        float4 r0 = res4[(size_t)n * 16 + hh8 * 2], r1 = res4[(size_t)n * 16 + hh8 * 2 + 1];
        o[0] += r0.x; o[1] += r0.y; o[2] += r0.z; o[3] += r0.w;
        o[4] += r1.x; o[5] += r1.y; o[6] += r1.z; o[7] += r1.w;
    }
    float4 lo = make_float4(o[0], o[1], o[2], o[3]);
    float4 hi = make_float4(o[4], o[5], o[6], o[7]);
    if (nvalid) {
        h4[(size_t)n * 16 + hh8 * 2]     = lo;
        h4[(size_t)n * 16 + hh8 * 2 + 1] = hi;
    }

    if (DOGEMM) {
        // same-wave LDS write->read (rows wv*8..wv*8+7 only): in-order, no barrier
        hrow[nl * 17 + hh8 * 2]     = lo;
        hrow[nl * 17 + hh8 * 2 + 1] = hi;
        const int hh = lane;
        const int nb = blockIdx.x * 32 + wv * 8;
        float acc[8];
#pragma unroll
        for (int s8 = 0; s8 < 8; ++s8) acc[s8] = 0.f;
#pragma unroll
        for (int k4 = 0; k4 < 16; ++k4) {
            float4 w = Wt[k4 * 65 + hh];
#pragma unroll
            for (int s8 = 0; s8 < 8; ++s8) {
                float4 hv = hrow[(wv * 8 + s8) * 17 + k4];   // wave-broadcast (free)
                acc[s8] += hv.x * w.x + hv.y * w.y + hv.z * w.z + hv.w * w.w;
            }
        }
#pragma unroll
        for (int s8 = 0; s8 < 8; ++s8) {
            int ns = nb + s8;
            if (ns < N_NODES) {
                float dd = rsqrtf((float)fill[ns] + 1.0f);
                gout[(size_t)ns * HID + hh] = __float2half(acc[s8] * dd);
            }
        }
    }
}

// ---------------- pool + final linear: one 1024-thread block per graph ----------------
__device__ __forceinline__ int lowerb(const int* __restrict__ b, int val) {
    int lo = 0, hi = N_NODES;
    while (lo < hi) {
        int mid = (lo + hi) >> 1;
        if (b[mid] < val) lo = mid + 1; else hi = mid;
    }
    return lo;
}

__global__ __launch_bounds__(1024) void k_poolfinal(const float* __restrict__ h,
                                                    const int* __restrict__ batch,
                                                    const float* __restrict__ lin_w,
                                                    const float* __restrict__ lin_b,
                                                    float* __restrict__ out) {
    __shared__ float red[16][HID];
    int g = blockIdx.x;
    int w = threadIdx.x >> 6;
    int hh = threadIdx.x & 63;
    int start = lowerb(batch, g);
    int end = lowerb(batch, g + 1);
    int len = end - start;
    float acc = 0.f;
    for (int n = start + w; n < end; n += 16) acc += h[n * HID + hh];
    red[w][hh] = acc;
    __syncthreads();
    if (w == 0) {
        float s = 0.f;
#pragma unroll
        for (int i = 0; i < 16; ++i) s += red[i][hh];
        float c = fmaxf((float)len, 1.0f);
        float v = (s / c) * lin_w[hh];
#pragma unroll
        for (int off = 32; off > 0; off >>= 1) v += __shfl_down(v, off);
        if (hh == 0) out[g] = v + lin_b[0];
    }
}

extern "C" void kernel_launch(void* const* d_in, const int* in_sizes, int n_in,
                              void* d_out, int out_size, void* d_ws, size_t ws_size,
                              hipStream_t stream) {
    const float* x     = (const float*)d_in[0];
    const int*   ei    = (const int*)d_in[1];
    const int*   batch = (const int*)d_in[2];
    const float* W_in  = (const float*)d_in[3];
    const float* W1    = (const float*)d_in[4];
    const float* b1    = (const float*)d_in[5];
    const float* Ws    = (const float*)d_in[6];
    const float* bs_   = (const float*)d_in[7];
    const float* bn_g  = (const float*)d_in[8];
    const float* bn_b  = (const float*)d_in[9];
    const float* bn_m  = (const float*)d_in[10];
    const float* bn_v  = (const float*)d_in[11];
    const float* lin_w = (const float*)d_in[12];
    const float* lin_b = (const float*)d_in[13];
    float* out = (float*)d_out;

    char* q = (char*)d_ws;
    int*            fill = (int*)q;             q += (size_t)50048 * 4;
    unsigned short* colp = (unsigned short*)q;  q += (size_t)N_NODES * MAXDEG * 2;
    __half*         g16a = (__half*)q;          q += (size_t)N_NODES * HID * 2;
    __half*         g16b = (__half*)q;          q += (size_t)N_NODES * HID * 2;
    float*          h    = (float*)q;           q += (size_t)N_NODES * HID * 4;

    const int NB_N  = NB256(N_NODES);
    const int NB_GA = (N_NODES + 31) / 32;   // 1563
    float4* h4 = (float4*)h;

    // zero fill, then fused dual-GEMM (identity + layer-1) with deferred-store edge placement
    k_zero<<<NB_N, 256, 0, stream>>>(fill);
    k_gemmedge<<<GE_NB, 256, 0, stream>>>(ei, fill, colp, x, W_in, W1, h, g16a);

    // layer 1: gather (per-source dinv; g16a unscaled) + fused gemm for layer 2
    k_gather_fused<true, true><<<NB_GA, 256, 0, stream>>>(
        g16a, colp, fill, b1, bn_g, bn_b, bn_m, bn_v,
        (const float4*)h, h4, Ws + 0 * HID * HID, g16b);

    // layers 2-4: gather (pre-scaled g16) + fused gemm for next layer
    k_gather_fused<false, true><<<NB_GA, 256, 0, stream>>>(
        g16b, colp, fill, bs_ + 0 * HID,
        bn_g + 1 * HID, bn_b + 1 * HID, bn_m + 1 * HID, bn_v + 1 * HID,
        (const float4*)h, h4, Ws + 1 * HID * HID, g16a);

    k_gather_fused<false, true><<<NB_GA, 256, 0, stream>>>(
        g16a, colp, fill, bs_ + 1 * HID,
        bn_g + 2 * HID, bn_b + 2 * HID, bn_m + 2 * HID, bn_v + 2 * HID,
        (const float4*)h, h4, Ws + 2 * HID * HID, g16b);

    k_gather_fused<false, true><<<NB_GA, 256, 0, stream>>>(
        g16b, colp, fill, bs_ + 2 * HID,
        bn_g + 3 * HID, bn_b + 3 * HID, bn_m + 3 * HID, bn_v + 3 * HID,
        (const float4*)h, h4, Ws + 3 * HID * HID, g16a);

    // layer 5: gather only (no residual, no next gemm)
    k_gather_fused<false, false><<<NB_GA, 256, 0, stream>>>(
        g16a, colp, fill, bs_ + 3 * HID,
        bn_g + 4 * HID, bn_b + 4 * HID, bn_m + 4 * HID, bn_v + 4 * HID,
        nullptr, h4, nullptr, nullptr);

    // pool + final
    k_poolfinal<<<N_GRAPHS, 1024, 0, stream>>>(h, batch, lin_w, lin_b, out);
}

// Round 5
// 524.150 us; speedup vs baseline: 2.7478x; 2.7478x over previous
//
#include <hip/hip_runtime.h>
#include <hip/hip_fp16.h>

#define N_NODES 50000
#define N_FEAT  128
#define HID     64
#define N_EDGES 800000
#define N_GRAPHS 64
#define MAXDEG  64
#define BN_EPS  1e-5f
#define NB256(n) (((n) + 255) / 256)

// ---------------- zero fill counters ----------------
__global__ __launch_bounds__(256) void k_zero(int* fill) {
    int i = blockIdx.x * 256 + threadIdx.x;
    if (i < N_NODES) fill[i] = 0;
}

// ---------------- fused dual-GEMM with piggybacked edge placement ----------------
// 2500 blocks x 20 nodes: stage x ONCE, compute BOTH x@W_in^T (fp32 h) and
// x@W1^T (fp16 g16). W chunks are software-pipelined through registers so the
// L2 load latency of chunk c+1 hides under the compute of chunk c.
#define GE_NB 2500
__global__ __launch_bounds__(256) void k_gemmedge(const int* __restrict__ ei,
                                                  int* fill, unsigned short* __restrict__ colp,
                                                  const float* __restrict__ x,
                                                  const float* __restrict__ W_in,
                                                  const float* __restrict__ W1,
                                                  float* __restrict__ h,
                                                  __half* __restrict__ g16) {
    __shared__ float4 Wt[2][8 * 65];   // 8 k4-slices of both W, stride 65 (conflict-free)
    __shared__ float4 xs[20 * 32];     // 20 node rows of x
    const int bid = blockIdx.x;
    const int t = threadIdx.x;

    // edge slice: issue atomics now, consume results after the GEMM
    const int ebase = bid * 320;
    int s1 = ei[ebase + t];
    int d1 = ei[N_EDGES + ebase + t];
    int k1 = atomicAdd(&fill[d1], 1);
    int s2 = 0, d2 = 0, k2 = MAXDEG;
    if (t < 64) {
        s2 = ei[ebase + 256 + t];
        d2 = ei[N_EDGES + ebase + 256 + t];
        k2 = atomicAdd(&fill[d2], 1);
    }

    // W chunk 0 prefetch into registers (each thread owns 2 slots of each W)
    const float4* W0v = (const float4*)W_in;
    const float4* W1v = (const float4*)W1;
    const int h2a = t >> 3, k4a = t & 7;
    const int h2b = h2a + 32;                 // second slot: i = t + 256
    float4 w0a = W0v[h2a * 32 + k4a];
    float4 w1a = W1v[h2a * 32 + k4a];
    float4 w0b = W0v[h2b * 32 + k4a];
    float4 w1b = W1v[h2b * 32 + k4a];

    const int base = bid * 20;
    const float4* xv = (const float4*)(x + (long long)base * N_FEAT);
    for (int i = t; i < 20 * 32; i += 256) xs[i] = xv[i];

    const int hh = t & 63;
    const int ng = t >> 6;
    float4 a0[5], a1[5];
#pragma unroll
    for (int j = 0; j < 5; ++j) {
        a0[j] = make_float4(0.f, 0.f, 0.f, 0.f);
        a1[j] = make_float4(0.f, 0.f, 0.f, 0.f);
    }

    for (int c = 0; c < 32; c += 8) {
        __syncthreads();  // WAR on Wt (also orders xs staging before first MAC)
        Wt[0][k4a * 65 + h2a] = w0a;  Wt[1][k4a * 65 + h2a] = w1a;
        Wt[0][k4a * 65 + h2b] = w0b;  Wt[1][k4a * 65 + h2b] = w1b;
        if (c + 8 < 32) {   // prefetch next chunk; latency hides under compute
            w0a = W0v[h2a * 32 + c + 8 + k4a]; w1a = W1v[h2a * 32 + c + 8 + k4a];
            w0b = W0v[h2b * 32 + c + 8 + k4a]; w1b = W1v[h2b * 32 + c + 8 + k4a];
        }
        __syncthreads();
#pragma unroll
        for (int k4 = 0; k4 < 8; ++k4) {
            float4 w0 = Wt[0][k4 * 65 + hh];
            float4 w1 = Wt[1][k4 * 65 + hh];
#pragma unroll
            for (int j = 0; j < 5; ++j) {
                float4 xx = xs[(ng + 4 * j) * 32 + c + k4];   // wave-broadcast
                a0[j].x += w0.x * xx.x; a0[j].y += w0.y * xx.y;
                a0[j].z += w0.z * xx.z; a0[j].w += w0.w * xx.w;
                a1[j].x += w1.x * xx.x; a1[j].y += w1.y * xx.y;
                a1[j].z += w1.z * xx.z; a1[j].w += w1.w * xx.w;
            }
        }
    }
#pragma unroll
    for (int j = 0; j < 5; ++j) {
        int node = base + ng + 4 * j;
        h[node * HID + hh]   = a0[j].x + a0[j].y + a0[j].z + a0[j].w;
        g16[node * HID + hh] = __float2half(a1[j].x + a1[j].y + a1[j].z + a1[j].w);
    }

    // deferred stores: atomic results long since returned
    if (k1 < MAXDEG) colp[d1 * MAXDEG + k1] = (unsigned short)s1;
    if (k2 < MAXDEG) colp[d2 * MAXDEG + k2] = (unsigned short)s2;
}

// ---- fp16 row accumulate, scaled (FMA — same cost as plain add) ----
__device__ __forceinline__ void acc8s(const uint4 r, float* a, float s) {
    float2 f0 = __half22float2(*(const __half2*)&r.x);
    float2 f1 = __half22float2(*(const __half2*)&r.y);
    float2 f2 = __half22float2(*(const __half2*)&r.z);
    float2 f3 = __half22float2(*(const __half2*)&r.w);
    a[0] += s * f0.x; a[1] += s * f0.y; a[2] += s * f1.x; a[3] += s * f1.y;
    a[4] += s * f2.x; a[5] += s * f2.y; a[6] += s * f3.x; a[7] += s * f3.y;
}

// ------ fused gather(+BN/ReLU/res) [+ per-wave GEMM], ONE node per 8-lane sub ------
// 1563 blocks x 32 nodes. Each lane owns one feature-octet of its sub's node.
// Spill fix vs R3/R4: #pragma unroll 1 on the rb loop — the compiler was fully
// unrolling 16 iterations and hoisting ~64 uint4 loads (256 VGPR / 1 GB scratch
// traffic). Body keeps 4 uint4 loads in flight, BN fold moved after the loop.
template <bool NSCALE, bool DOGEMM>
__global__ __launch_bounds__(256) void k_gather_fused(const __half* __restrict__ gin,
                                                      const unsigned short* __restrict__ colp,
                                                      const int* __restrict__ fill,
                                                      const float* __restrict__ b,
                                                      const float* __restrict__ gamma,
                                                      const float* __restrict__ beta,
                                                      const float* __restrict__ mean,
                                                      const float* __restrict__ var,
                                                      const float4* __restrict__ res4,
                                                      float4* __restrict__ h4,
                                                      const float* __restrict__ W,
                                                      __half* __restrict__ gout) {
    __shared__ float4 Wt[DOGEMM ? 16 * 65 : 1];
    __shared__ float4 hrow[DOGEMM ? 32 * 17 : 1];   // stride 17

    const int t = threadIdx.x;
    const int wv = t >> 6;
    const int lane = t & 63;
    const int hh8 = lane & 7;       // feature octet
    const int sub = lane >> 3;      // node slot within wave
    const int nl = wv * 8 + sub;    // local node 0..31
    const int n = blockIdx.x * 32 + nl;
    const bool nvalid = (n < N_NODES);

    if (DOGEMM) {
        const float4* Wv = (const float4*)W;
        for (int i = t; i < HID * 16; i += 256) {
            int h2 = i >> 4, k4 = i & 15;
            Wt[k4 * 65 + h2] = Wv[i];
        }
        __syncthreads();   // only block barrier: Wt visible before any use
    }

    const uint4* gv = (const uint4*)gin;  // row = 8 x uint4 (128 B)
    const int fl = nvalid ? fill[n] : 0;
    const int deg = fl < MAXDEG ? fl : MAXDEG;

    float a[8];
#pragma unroll
    for (int i = 0; i < 8; ++i) a[i] = 0.f;

    const unsigned long long* cp4 =
        (const unsigned long long*)(colp + (size_t)n * MAXDEG);  // deref only if deg>0

#pragma unroll 1
    for (int rb = 0; rb < MAXDEG; rb += 4) {
        if (!__any(rb < deg)) break;          // wave-uniform exit
        if (rb < deg) {                       // sub-uniform mask (8 lanes alike)
            unsigned long long cc = cp4[rb >> 2];   // 4 packed cols, broadcast
            int c[4]; float s[4]; uint4 v[4];
#pragma unroll
            for (int k = 0; k < 4; ++k) {
                bool pk = (rb + k) < deg;
                c[k] = pk ? (int)((cc >> (16 * k)) & 0xFFFFull) : 0;
                if (NSCALE) s[k] = pk ? rsqrtf((float)fill[c[k]] + 1.0f) : 0.0f;
                else        s[k] = pk ? 1.0f : 0.0f;
            }
#pragma unroll
            for (int k = 0; k < 4; ++k) v[k] = gv[(size_t)c[k] * 8 + hh8];
#pragma unroll
            for (int k = 0; k < 4; ++k) acc8s(v[k], a, s[k]);
        }
    }

    const float di = rsqrtf((float)fl + 1.0f);
    if (nvalid) acc8s(gv[(size_t)n * 8 + hh8], a, NSCALE ? di : 1.0f);  // self loop

    // BN fold (post-loop; params from L2): o = a*di*SC + SH
    float o[8];
    {
        float4 b0 = ((const float4*)b)[hh8 * 2],     b1 = ((const float4*)b)[hh8 * 2 + 1];
        float4 g0 = ((const float4*)gamma)[hh8 * 2], g1 = ((const float4*)gamma)[hh8 * 2 + 1];
        float4 e0 = ((const float4*)beta)[hh8 * 2],  e1 = ((const float4*)beta)[hh8 * 2 + 1];
        float4 m0 = ((const float4*)mean)[hh8 * 2],  m1 = ((const float4*)mean)[hh8 * 2 + 1];
        float4 v0 = ((const float4*)var)[hh8 * 2],   v1 = ((const float4*)var)[hh8 * 2 + 1];
        float bb[8] = {b0.x, b0.y, b0.z, b0.w, b1.x, b1.y, b1.z, b1.w};
        float gg[8] = {g0.x, g0.y, g0.z, g0.w, g1.x, g1.y, g1.z, g1.w};
        float ee[8] = {e0.x, e0.y, e0.z, e0.w, e1.x, e1.y, e1.z, e1.w};
        float mm[8] = {m0.x, m0.y, m0.z, m0.w, m1.x, m1.y, m1.z, m1.w};
        float vv[8] = {v0.x, v0.y, v0.z, v0.w, v1.x, v1.y, v1.z, v1.w};
#pragma unroll
        for (int i = 0; i < 8; ++i) {
            float sc = gg[i] * rsqrtf(vv[i] + BN_EPS);
            float sh = (bb[i] - mm[i]) * sc + ee[i];
            o[i] = fmaxf(fmaf(a[i] * di, sc, sh), 0.f);
        }
    }

    if (res4 != nullptr && nvalid) {
        float4 r0 = res4[(size_t)n * 16 + hh8 * 2], r1 = res4[(size_t)n * 16 + hh8 * 2 + 1];
        o[0] += r0.x; o[1] += r0.y; o[2] += r0.z; o[3] += r0.w;
        o[4] += r1.x; o[5] += r1.y; o[6] += r1.z; o[7] += r1.w;
    }
    float4 lo = make_float4(o[0], o[1], o[2], o[3]);
    float4 hi = make_float4(o[4], o[5], o[6], o[7]);
    if (nvalid) {
        h4[(size_t)n * 16 + hh8 * 2]     = lo;
        h4[(size_t)n * 16 + hh8 * 2 + 1] = hi;
    }

    if (DOGEMM) {
        // same-wave LDS write->read (rows wv*8..wv*8+7 only): in-order, no barrier
        hrow[nl * 17 + hh8 * 2]     = lo;
        hrow[nl * 17 + hh8 * 2 + 1] = hi;
        const int hh = lane;
        const int nb = blockIdx.x * 32 + wv * 8;
        float acc[8];
#pragma unroll
        for (int s8 = 0; s8 < 8; ++s8) acc[s8] = 0.f;
#pragma unroll
        for (int k4 = 0; k4 < 16; ++k4) {
            float4 w = Wt[k4 * 65 + hh];
#pragma unroll
            for (int s8 = 0; s8 < 8; ++s8) {
                float4 hv = hrow[(wv * 8 + s8) * 17 + k4];   // wave-broadcast (free)
                acc[s8] += hv.x * w.x + hv.y * w.y + hv.z * w.z + hv.w * w.w;
            }
        }
#pragma unroll
        for (int s8 = 0; s8 < 8; ++s8) {
            int ns = nb + s8;
            if (ns < N_NODES) {
                float dd = rsqrtf((float)fill[ns] + 1.0f);
                gout[(size_t)ns * HID + hh] = __float2half(acc[s8] * dd);
            }
        }
    }
}

// ---------------- pool + final linear: one 1024-thread block per graph ----------------
__device__ __forceinline__ int lowerb(const int* __restrict__ b, int val) {
    int lo = 0, hi = N_NODES;
    while (lo < hi) {
        int mid = (lo + hi) >> 1;
        if (b[mid] < val) lo = mid + 1; else hi = mid;
    }
    return lo;
}

__global__ __launch_bounds__(1024) void k_poolfinal(const float* __restrict__ h,
                                                    const int* __restrict__ batch,
                                                    const float* __restrict__ lin_w,
                                                    const float* __restrict__ lin_b,
                                                    float* __restrict__ out) {
    __shared__ float red[16][HID];
    int g = blockIdx.x;
    int w = threadIdx.x >> 6;
    int hh = threadIdx.x & 63;
    int start = lowerb(batch, g);
    int end = lowerb(batch, g + 1);
    int len = end - start;
    float acc = 0.f;
    for (int n = start + w; n < end; n += 16) acc += h[n * HID + hh];
    red[w][hh] = acc;
    __syncthreads();
    if (w == 0) {
        float s = 0.f;
#pragma unroll
        for (int i = 0; i < 16; ++i) s += red[i][hh];
        float c = fmaxf((float)len, 1.0f);
        float v = (s / c) * lin_w[hh];
#pragma unroll
        for (int off = 32; off > 0; off >>= 1) v += __shfl_down(v, off);
        if (hh == 0) out[g] = v + lin_b[0];
    }
}

extern "C" void kernel_launch(void* const* d_in, const int* in_sizes, int n_in,
                              void* d_out, int out_size, void* d_ws, size_t ws_size,
                              hipStream_t stream) {
    const float* x     = (const float*)d_in[0];
    const int*   ei    = (const int*)d_in[1];
    const int*   batch = (const int*)d_in[2];
    const float* W_in  = (const float*)d_in[3];
    const float* W1    = (const float*)d_in[4];
    const float* b1    = (const float*)d_in[5];
    const float* Ws    = (const float*)d_in[6];
    const float* bs_   = (const float*)d_in[7];
    const float* bn_g  = (const float*)d_in[8];
    const float* bn_b  = (const float*)d_in[9];
    const float* bn_m  = (const float*)d_in[10];
    const float* bn_v  = (const float*)d_in[11];
    const float* lin_w = (const float*)d_in[12];
    const float* lin_b = (const float*)d_in[13];
    float* out = (float*)d_out;

    char* q = (char*)d_ws;
    int*            fill = (int*)q;             q += (size_t)50048 * 4;
    unsigned short* colp = (unsigned short*)q;  q += (size_t)N_NODES * MAXDEG * 2;
    __half*         g16a = (__half*)q;          q += (size_t)N_NODES * HID * 2;
    __half*         g16b = (__half*)q;          q += (size_t)N_NODES * HID * 2;
    float*          h    = (float*)q;           q += (size_t)N_NODES * HID * 4;

    const int NB_N  = NB256(N_NODES);
    const int NB_GA = (N_NODES + 31) / 32;   // 1563
    float4* h4 = (float4*)h;

    // zero fill, then fused dual-GEMM (identity + layer-1) with deferred-store edge placement
    k_zero<<<NB_N, 256, 0, stream>>>(fill);
    k_gemmedge<<<GE_NB, 256, 0, stream>>>(ei, fill, colp, x, W_in, W1, h, g16a);

    // layer 1: gather (per-source dinv; g16a unscaled) + fused gemm for layer 2
    k_gather_fused<true, true><<<NB_GA, 256, 0, stream>>>(
        g16a, colp, fill, b1, bn_g, bn_b, bn_m, bn_v,
        (const float4*)h, h4, Ws + 0 * HID * HID, g16b);

    // layers 2-4: gather (pre-scaled g16) + fused gemm for next layer
    k_gather_fused<false, true><<<NB_GA, 256, 0, stream>>>(
        g16b, colp, fill, bs_ + 0 * HID,
        bn_g + 1 * HID, bn_b + 1 * HID, bn_m + 1 * HID, bn_v + 1 * HID,
        (const float4*)h, h4, Ws + 1 * HID * HID, g16a);

    k_gather_fused<false, true><<<NB_GA, 256, 0, stream>>>(
        g16a, colp, fill, bs_ + 1 * HID,
        bn_g + 2 * HID, bn_b + 2 * HID, bn_m + 2 * HID, bn_v + 2 * HID,
        (const float4*)h, h4, Ws + 2 * HID * HID, g16b);

    k_gather_fused<false, true><<<NB_GA, 256, 0, stream>>>(
        g16b, colp, fill, bs_ + 2 * HID,
        bn_g + 3 * HID, bn_b + 3 * HID, bn_m + 3 * HID, bn_v + 3 * HID,
        (const float4*)h, h4, Ws + 3 * HID * HID, g16a);

    // layer 5: gather only (no residual, no next gemm)
    k_gather_fused<false, false><<<NB_GA, 256, 0, stream>>>(
        g16a, colp, fill, bs_ + 3 * HID,
        bn_g + 4 * HID, bn_b + 4 * HID, bn_m + 4 * HID, bn_v + 4 * HID,
        nullptr, h4, nullptr, nullptr);

    // pool + final
    k_poolfinal<<<N_GRAPHS, 1024, 0, stream>>>(h, batch, lin_w, lin_b, out);
}

// Round 6
// 322.951 us; speedup vs baseline: 4.4597x; 1.6230x over previous
//
#include <hip/hip_runtime.h>
#include <hip/hip_fp16.h>

#define N_NODES 50000
#define N_FEAT  128
#define HID     64
#define N_EDGES 800000
#define N_GRAPHS 64
#define MAXDEG  64
#define BN_EPS  1e-5f
#define NB256(n) (((n) + 255) / 256)

// ---------------- zero fill counters ----------------
__global__ __launch_bounds__(256) void k_zero(int* fill) {
    int i = blockIdx.x * 256 + threadIdx.x;
    if (i < N_NODES) fill[i] = 0;
}

// ---------------- fused dual-GEMM with piggybacked edge placement ----------------
// 2500 blocks x 20 nodes: stage x ONCE, compute BOTH x@W_in^T (fp32 h) and
// x@W1^T (fp16 g16). W chunks are software-pipelined through registers so the
// L2 load latency of chunk c+1 hides under the compute of chunk c.
#define GE_NB 2500
__global__ __launch_bounds__(256) void k_gemmedge(const int* __restrict__ ei,
                                                  int* fill, unsigned short* __restrict__ colp,
                                                  const float* __restrict__ x,
                                                  const float* __restrict__ W_in,
                                                  const float* __restrict__ W1,
                                                  float* __restrict__ h,
                                                  __half* __restrict__ g16) {
    __shared__ float4 Wt[2][8 * 65];   // 8 k4-slices of both W, stride 65 (conflict-free)
    __shared__ float4 xs[20 * 32];     // 20 node rows of x
    const int bid = blockIdx.x;
    const int t = threadIdx.x;

    // edge slice: issue atomics now, consume results after the GEMM
    const int ebase = bid * 320;
    int s1 = ei[ebase + t];
    int d1 = ei[N_EDGES + ebase + t];
    int k1 = atomicAdd(&fill[d1], 1);
    int s2 = 0, d2 = 0, k2 = MAXDEG;
    if (t < 64) {
        s2 = ei[ebase + 256 + t];
        d2 = ei[N_EDGES + ebase + 256 + t];
        k2 = atomicAdd(&fill[d2], 1);
    }

    // W chunk 0 prefetch into registers (each thread owns 2 slots of each W)
    const float4* W0v = (const float4*)W_in;
    const float4* W1v = (const float4*)W1;
    const int h2a = t >> 3, k4a = t & 7;
    const int h2b = h2a + 32;                 // second slot: i = t + 256
    float4 w0a = W0v[h2a * 32 + k4a];
    float4 w1a = W1v[h2a * 32 + k4a];
    float4 w0b = W0v[h2b * 32 + k4a];
    float4 w1b = W1v[h2b * 32 + k4a];

    const int base = bid * 20;
    const float4* xv = (const float4*)(x + (long long)base * N_FEAT);
    for (int i = t; i < 20 * 32; i += 256) xs[i] = xv[i];

    const int hh = t & 63;
    const int ng = t >> 6;
    float4 a0[5], a1[5];
#pragma unroll
    for (int j = 0; j < 5; ++j) {
        a0[j] = make_float4(0.f, 0.f, 0.f, 0.f);
        a1[j] = make_float4(0.f, 0.f, 0.f, 0.f);
    }

    for (int c = 0; c < 32; c += 8) {
        __syncthreads();  // WAR on Wt (also orders xs staging before first MAC)
        Wt[0][k4a * 65 + h2a] = w0a;  Wt[1][k4a * 65 + h2a] = w1a;
        Wt[0][k4a * 65 + h2b] = w0b;  Wt[1][k4a * 65 + h2b] = w1b;
        if (c + 8 < 32) {   // prefetch next chunk; latency hides under compute
            w0a = W0v[h2a * 32 + c + 8 + k4a]; w1a = W1v[h2a * 32 + c + 8 + k4a];
            w0b = W0v[h2b * 32 + c + 8 + k4a]; w1b = W1v[h2b * 32 + c + 8 + k4a];
        }
        __syncthreads();
#pragma unroll
        for (int k4 = 0; k4 < 8; ++k4) {
            float4 w0 = Wt[0][k4 * 65 + hh];
            float4 w1 = Wt[1][k4 * 65 + hh];
#pragma unroll
            for (int j = 0; j < 5; ++j) {
                float4 xx = xs[(ng + 4 * j) * 32 + c + k4];   // wave-broadcast
                a0[j].x += w0.x * xx.x; a0[j].y += w0.y * xx.y;
                a0[j].z += w0.z * xx.z; a0[j].w += w0.w * xx.w;
                a1[j].x += w1.x * xx.x; a1[j].y += w1.y * xx.y;
                a1[j].z += w1.z * xx.z; a1[j].w += w1.w * xx.w;
            }
        }
    }
#pragma unroll
    for (int j = 0; j < 5; ++j) {
        int node = base + ng + 4 * j;
        h[node * HID + hh]   = a0[j].x + a0[j].y + a0[j].z + a0[j].w;
        g16[node * HID + hh] = __float2half(a1[j].x + a1[j].y + a1[j].z + a1[j].w);
    }

    // deferred stores: atomic results long since returned
    if (k1 < MAXDEG) colp[d1 * MAXDEG + k1] = (unsigned short)s1;
    if (k2 < MAXDEG) colp[d2 * MAXDEG + k2] = (unsigned short)s2;
}

// ---- fp16 row accumulate, scaled (FMA — same cost as plain add) ----
__device__ __forceinline__ void acc8s(const uint4 r, float* a, float s) {
    float2 f0 = __half22float2(*(const __half2*)&r.x);
    float2 f1 = __half22float2(*(const __half2*)&r.y);
    float2 f2 = __half22float2(*(const __half2*)&r.z);
    float2 f3 = __half22float2(*(const __half2*)&r.w);
    a[0] += s * f0.x; a[1] += s * f0.y; a[2] += s * f1.x; a[3] += s * f1.y;
    a[4] += s * f2.x; a[5] += s * f2.y; a[6] += s * f3.x; a[7] += s * f3.y;
}

// ------ fused gather(+BN/ReLU/res) [+ per-wave GEMM], ONE node per 8-lane sub ------
// 1563 blocks x 32 nodes. Each lane owns one feature-octet of its sub's node.
// R5 post-mortem: rb-loop unroll 1 wasn't enough — VGPR stayed 256. Remaining
// fully-unrolled block = DOGEMM epilogue (16 k4 x (1 Wt + 8 hrow) = 144 float4
// LDS loads/lane, scheduler hoists them all). Fix: #pragma unroll 2 there.
template <bool NSCALE, bool DOGEMM>
__global__ __launch_bounds__(256) void k_gather_fused(const __half* __restrict__ gin,
                                                      const unsigned short* __restrict__ colp,
                                                      const int* __restrict__ fill,
                                                      const float* __restrict__ b,
                                                      const float* __restrict__ gamma,
                                                      const float* __restrict__ beta,
                                                      const float* __restrict__ mean,
                                                      const float* __restrict__ var,
                                                      const float4* __restrict__ res4,
                                                      float4* __restrict__ h4,
                                                      const float* __restrict__ W,
                                                      __half* __restrict__ gout) {
    __shared__ float4 Wt[DOGEMM ? 16 * 65 : 1];
    __shared__ float4 hrow[DOGEMM ? 32 * 17 : 1];   // stride 17

    const int t = threadIdx.x;
    const int wv = t >> 6;
    const int lane = t & 63;
    const int hh8 = lane & 7;       // feature octet
    const int sub = lane >> 3;      // node slot within wave
    const int nl = wv * 8 + sub;    // local node 0..31
    const int n = blockIdx.x * 32 + nl;
    const bool nvalid = (n < N_NODES);

    if (DOGEMM) {
        const float4* Wv = (const float4*)W;
        for (int i = t; i < HID * 16; i += 256) {
            int h2 = i >> 4, k4 = i & 15;
            Wt[k4 * 65 + h2] = Wv[i];
        }
        __syncthreads();   // only block barrier: Wt visible before any use
    }

    const uint4* gv = (const uint4*)gin;  // row = 8 x uint4 (128 B)
    const int fl = nvalid ? fill[n] : 0;
    const int deg = fl < MAXDEG ? fl : MAXDEG;

    float a[8];
#pragma unroll
    for (int i = 0; i < 8; ++i) a[i] = 0.f;

    const unsigned long long* cp4 =
        (const unsigned long long*)(colp + (size_t)n * MAXDEG);  // deref only if deg>0

#pragma unroll 1
    for (int rb = 0; rb < MAXDEG; rb += 4) {
        if (!__any(rb < deg)) break;          // wave-uniform exit
        if (rb < deg) {                       // sub-uniform mask (8 lanes alike)
            unsigned long long cc = cp4[rb >> 2];   // 4 packed cols, broadcast
            int c[4]; float s[4]; uint4 v[4];
#pragma unroll
            for (int k = 0; k < 4; ++k) {
                bool pk = (rb + k) < deg;
                c[k] = pk ? (int)((cc >> (16 * k)) & 0xFFFFull) : 0;
                if (NSCALE) s[k] = pk ? rsqrtf((float)fill[c[k]] + 1.0f) : 0.0f;
                else        s[k] = pk ? 1.0f : 0.0f;
            }
#pragma unroll
            for (int k = 0; k < 4; ++k) v[k] = gv[(size_t)c[k] * 8 + hh8];
#pragma unroll
            for (int k = 0; k < 4; ++k) acc8s(v[k], a, s[k]);
        }
    }

    const float di = rsqrtf((float)fl + 1.0f);
    if (nvalid) acc8s(gv[(size_t)n * 8 + hh8], a, NSCALE ? di : 1.0f);  // self loop

    // BN fold (post-loop; params from L2): o = a*di*SC + SH
    float o[8];
    {
        float4 b0 = ((const float4*)b)[hh8 * 2],     b1 = ((const float4*)b)[hh8 * 2 + 1];
        float4 g0 = ((const float4*)gamma)[hh8 * 2], g1 = ((const float4*)gamma)[hh8 * 2 + 1];
        float4 e0 = ((const float4*)beta)[hh8 * 2],  e1 = ((const float4*)beta)[hh8 * 2 + 1];
        float4 m0 = ((const float4*)mean)[hh8 * 2],  m1 = ((const float4*)mean)[hh8 * 2 + 1];
        float4 v0 = ((const float4*)var)[hh8 * 2],   v1 = ((const float4*)var)[hh8 * 2 + 1];
        float bb[8] = {b0.x, b0.y, b0.z, b0.w, b1.x, b1.y, b1.z, b1.w};
        float gg[8] = {g0.x, g0.y, g0.z, g0.w, g1.x, g1.y, g1.z, g1.w};
        float ee[8] = {e0.x, e0.y, e0.z, e0.w, e1.x, e1.y, e1.z, e1.w};
        float mm[8] = {m0.x, m0.y, m0.z, m0.w, m1.x, m1.y, m1.z, m1.w};
        float vv[8] = {v0.x, v0.y, v0.z, v0.w, v1.x, v1.y, v1.z, v1.w};
#pragma unroll
        for (int i = 0; i < 8; ++i) {
            float sc = gg[i] * rsqrtf(vv[i] + BN_EPS);
            float sh = (bb[i] - mm[i]) * sc + ee[i];
            o[i] = fmaxf(fmaf(a[i] * di, sc, sh), 0.f);
        }
    }

    if (res4 != nullptr && nvalid) {
        float4 r0 = res4[(size_t)n * 16 + hh8 * 2], r1 = res4[(size_t)n * 16 + hh8 * 2 + 1];
        o[0] += r0.x; o[1] += r0.y; o[2] += r0.z; o[3] += r0.w;
        o[4] += r1.x; o[5] += r1.y; o[6] += r1.z; o[7] += r1.w;
    }
    float4 lo = make_float4(o[0], o[1], o[2], o[3]);
    float4 hi = make_float4(o[4], o[5], o[6], o[7]);
    if (nvalid) {
        h4[(size_t)n * 16 + hh8 * 2]     = lo;
        h4[(size_t)n * 16 + hh8 * 2 + 1] = hi;
    }

    if (DOGEMM) {
        // same-wave LDS write->read (rows wv*8..wv*8+7 only): in-order, no barrier
        hrow[nl * 17 + hh8 * 2]     = lo;
        hrow[nl * 17 + hh8 * 2 + 1] = hi;
        const int hh = lane;
        const int nb = blockIdx.x * 32 + wv * 8;
        float acc[8];
#pragma unroll
        for (int s8 = 0; s8 < 8; ++s8) acc[s8] = 0.f;
#pragma unroll 2
        for (int k4 = 0; k4 < 16; ++k4) {
            float4 w = Wt[k4 * 65 + hh];
#pragma unroll
            for (int s8 = 0; s8 < 8; ++s8) {
                float4 hv = hrow[(wv * 8 + s8) * 17 + k4];   // wave-broadcast (free)
                acc[s8] += hv.x * w.x + hv.y * w.y + hv.z * w.z + hv.w * w.w;
            }
        }
#pragma unroll
        for (int s8 = 0; s8 < 8; ++s8) {
            int ns = nb + s8;
            if (ns < N_NODES) {
                float dd = rsqrtf((float)fill[ns] + 1.0f);
                gout[(size_t)ns * HID + hh] = __float2half(acc[s8] * dd);
            }
        }
    }
}

// ---------------- pool + final linear: one 1024-thread block per graph ----------------
__device__ __forceinline__ int lowerb(const int* __restrict__ b, int val) {
    int lo = 0, hi = N_NODES;
    while (lo < hi) {
        int mid = (lo + hi) >> 1;
        if (b[mid] < val) lo = mid + 1; else hi = mid;
    }
    return lo;
}

__global__ __launch_bounds__(1024) void k_poolfinal(const float* __restrict__ h,
                                                    const int* __restrict__ batch,
                                                    const float* __restrict__ lin_w,
                                                    const float* __restrict__ lin_b,
                                                    float* __restrict__ out) {
    __shared__ float red[16][HID];
    int g = blockIdx.x;
    int w = threadIdx.x >> 6;
    int hh = threadIdx.x & 63;
    int start = lowerb(batch, g);
    int end = lowerb(batch, g + 1);
    int len = end - start;
    float acc = 0.f;
    for (int n = start + w; n < end; n += 16) acc += h[n * HID + hh];
    red[w][hh] = acc;
    __syncthreads();
    if (w == 0) {
        float s = 0.f;
#pragma unroll
        for (int i = 0; i < 16; ++i) s += red[i][hh];
        float c = fmaxf((float)len, 1.0f);
        float v = (s / c) * lin_w[hh];
#pragma unroll
        for (int off = 32; off > 0; off >>= 1) v += __shfl_down(v, off);
        if (hh == 0) out[g] = v + lin_b[0];
    }
}

extern "C" void kernel_launch(void* const* d_in, const int* in_sizes, int n_in,
                              void* d_out, int out_size, void* d_ws, size_t ws_size,
                              hipStream_t stream) {
    const float* x     = (const float*)d_in[0];
    const int*   ei    = (const int*)d_in[1];
    const int*   batch = (const int*)d_in[2];
    const float* W_in  = (const float*)d_in[3];
    const float* W1    = (const float*)d_in[4];
    const float* b1    = (const float*)d_in[5];
    const float* Ws    = (const float*)d_in[6];
    const float* bs_   = (const float*)d_in[7];
    const float* bn_g  = (const float*)d_in[8];
    const float* bn_b  = (const float*)d_in[9];
    const float* bn_m  = (const float*)d_in[10];
    const float* bn_v  = (const float*)d_in[11];
    const float* lin_w = (const float*)d_in[12];
    const float* lin_b = (const float*)d_in[13];
    float* out = (float*)d_out;

    char* q = (char*)d_ws;
    int*            fill = (int*)q;             q += (size_t)50048 * 4;
    unsigned short* colp = (unsigned short*)q;  q += (size_t)N_NODES * MAXDEG * 2;
    __half*         g16a = (__half*)q;          q += (size_t)N_NODES * HID * 2;
    __half*         g16b = (__half*)q;          q += (size_t)N_NODES * HID * 2;
    float*          h    = (float*)q;           q += (size_t)N_NODES * HID * 4;

    const int NB_N  = NB256(N_NODES);
    const int NB_GA = (N_NODES + 31) / 32;   // 1563
    float4* h4 = (float4*)h;

    // zero fill, then fused dual-GEMM (identity + layer-1) with deferred-store edge placement
    k_zero<<<NB_N, 256, 0, stream>>>(fill);
    k_gemmedge<<<GE_NB, 256, 0, stream>>>(ei, fill, colp, x, W_in, W1, h, g16a);

    // layer 1: gather (per-source dinv; g16a unscaled) + fused gemm for layer 2
    k_gather_fused<true, true><<<NB_GA, 256, 0, stream>>>(
        g16a, colp, fill, b1, bn_g, bn_b, bn_m, bn_v,
        (const float4*)h, h4, Ws + 0 * HID * HID, g16b);

    // layers 2-4: gather (pre-scaled g16) + fused gemm for next layer
    k_gather_fused<false, true><<<NB_GA, 256, 0, stream>>>(
        g16b, colp, fill, bs_ + 0 * HID,
        bn_g + 1 * HID, bn_b + 1 * HID, bn_m + 1 * HID, bn_v + 1 * HID,
        (const float4*)h, h4, Ws + 1 * HID * HID, g16a);

    k_gather_fused<false, true><<<NB_GA, 256, 0, stream>>>(
        g16a, colp, fill, bs_ + 1 * HID,
        bn_g + 2 * HID, bn_b + 2 * HID, bn_m + 2 * HID, bn_v + 2 * HID,
        (const float4*)h, h4, Ws + 2 * HID * HID, g16b);

    k_gather_fused<false, true><<<NB_GA, 256, 0, stream>>>(
        g16b, colp, fill, bs_ + 2 * HID,
        bn_g + 3 * HID, bn_b + 3 * HID, bn_m + 3 * HID, bn_v + 3 * HID,
        (const float4*)h, h4, Ws + 3 * HID * HID, g16a);

    // layer 5: gather only (no residual, no next gemm)
    k_gather_fused<false, false><<<NB_GA, 256, 0, stream>>>(
        g16a, colp, fill, bs_ + 3 * HID,
        bn_g + 4 * HID, bn_b + 4 * HID, bn_m + 4 * HID, bn_v + 4 * HID,
        nullptr, h4, nullptr, nullptr);

    // pool + final
    k_poolfinal<<<N_GRAPHS, 1024, 0, stream>>>(h, batch, lin_w, lin_b, out);
}

// Round 7
// 314.922 us; speedup vs baseline: 4.5734x; 1.0255x over previous
//
#include <hip/hip_runtime.h>
#include <hip/hip_fp16.h>

#define N_NODES 50000
#define N_FEAT  128
#define HID     64
#define N_EDGES 800000
#define N_GRAPHS 64
#define MAXDEG  64
#define BN_EPS  1e-5f
#define NB256(n) (((n) + 255) / 256)

// ---------------- zero fill counters ----------------
__global__ __launch_bounds__(256) void k_zero(int* fill) {
    int i = blockIdx.x * 256 + threadIdx.x;
    if (i < N_NODES) fill[i] = 0;
}

// ---------------- fused dual-GEMM with piggybacked edge placement ----------------
// 2500 blocks x 20 nodes: stage x ONCE, compute BOTH x@W_in^T (fp32 h) and
// x@W1^T (fp16 g16). W chunks are software-pipelined through registers so the
// L2 load latency of chunk c+1 hides under the compute of chunk c.
#define GE_NB 2500
__global__ __launch_bounds__(256) void k_gemmedge(const int* __restrict__ ei,
                                                  int* fill, unsigned short* __restrict__ colp,
                                                  const float* __restrict__ x,
                                                  const float* __restrict__ W_in,
                                                  const float* __restrict__ W1,
                                                  float* __restrict__ h,
                                                  __half* __restrict__ g16) {
    __shared__ float4 Wt[2][8 * 65];   // 8 k4-slices of both W, stride 65 (conflict-free)
    __shared__ float4 xs[20 * 32];     // 20 node rows of x
    const int bid = blockIdx.x;
    const int t = threadIdx.x;

    // edge slice: issue atomics now, consume results after the GEMM
    const int ebase = bid * 320;
    int s1 = ei[ebase + t];
    int d1 = ei[N_EDGES + ebase + t];
    int k1 = atomicAdd(&fill[d1], 1);
    int s2 = 0, d2 = 0, k2 = MAXDEG;
    if (t < 64) {
        s2 = ei[ebase + 256 + t];
        d2 = ei[N_EDGES + ebase + 256 + t];
        k2 = atomicAdd(&fill[d2], 1);
    }

    // W chunk 0 prefetch into registers (each thread owns 2 slots of each W)
    const float4* W0v = (const float4*)W_in;
    const float4* W1v = (const float4*)W1;
    const int h2a = t >> 3, k4a = t & 7;
    const int h2b = h2a + 32;                 // second slot: i = t + 256
    float4 w0a = W0v[h2a * 32 + k4a];
    float4 w1a = W1v[h2a * 32 + k4a];
    float4 w0b = W0v[h2b * 32 + k4a];
    float4 w1b = W1v[h2b * 32 + k4a];

    const int base = bid * 20;
    const float4* xv = (const float4*)(x + (long long)base * N_FEAT);
    for (int i = t; i < 20 * 32; i += 256) xs[i] = xv[i];

    const int hh = t & 63;
    const int ng = t >> 6;
    float4 a0[5], a1[5];
#pragma unroll
    for (int j = 0; j < 5; ++j) {
        a0[j] = make_float4(0.f, 0.f, 0.f, 0.f);
        a1[j] = make_float4(0.f, 0.f, 0.f, 0.f);
    }

    for (int c = 0; c < 32; c += 8) {
        __syncthreads();  // WAR on Wt (also orders xs staging before first MAC)
        Wt[0][k4a * 65 + h2a] = w0a;  Wt[1][k4a * 65 + h2a] = w1a;
        Wt[0][k4a * 65 + h2b] = w0b;  Wt[1][k4a * 65 + h2b] = w1b;
        if (c + 8 < 32) {   // prefetch next chunk; latency hides under compute
            w0a = W0v[h2a * 32 + c + 8 + k4a]; w1a = W1v[h2a * 32 + c + 8 + k4a];
            w0b = W0v[h2b * 32 + c + 8 + k4a]; w1b = W1v[h2b * 32 + c + 8 + k4a];
        }
        __syncthreads();
#pragma unroll
        for (int k4 = 0; k4 < 8; ++k4) {
            float4 w0 = Wt[0][k4 * 65 + hh];
            float4 w1 = Wt[1][k4 * 65 + hh];
#pragma unroll
            for (int j = 0; j < 5; ++j) {
                float4 xx = xs[(ng + 4 * j) * 32 + c + k4];   // wave-broadcast
                a0[j].x += w0.x * xx.x; a0[j].y += w0.y * xx.y;
                a0[j].z += w0.z * xx.z; a0[j].w += w0.w * xx.w;
                a1[j].x += w1.x * xx.x; a1[j].y += w1.y * xx.y;
                a1[j].z += w1.z * xx.z; a1[j].w += w1.w * xx.w;
            }
        }
    }
#pragma unroll
    for (int j = 0; j < 5; ++j) {
        int node = base + ng + 4 * j;
        h[node * HID + hh]   = a0[j].x + a0[j].y + a0[j].z + a0[j].w;
        g16[node * HID + hh] = __float2half(a1[j].x + a1[j].y + a1[j].z + a1[j].w);
    }

    // deferred stores: atomic results long since returned
    if (k1 < MAXDEG) colp[d1 * MAXDEG + k1] = (unsigned short)s1;
    if (k2 < MAXDEG) colp[d2 * MAXDEG + k2] = (unsigned short)s2;
}

// ---- fp16 row accumulate, scaled (FMA — same cost as plain add) ----
__device__ __forceinline__ void acc8s(const uint4 r, float* a, float s) {
    float2 f0 = __half22float2(*(const __half2*)&r.x);
    float2 f1 = __half22float2(*(const __half2*)&r.y);
    float2 f2 = __half22float2(*(const __half2*)&r.z);
    float2 f3 = __half22float2(*(const __half2*)&r.w);
    a[0] += s * f0.x; a[1] += s * f0.y; a[2] += s * f1.x; a[3] += s * f1.y;
    a[4] += s * f2.x; a[5] += s * f2.y; a[6] += s * f3.x; a[7] += s * f3.y;
}

// ------ fused gather(+BN/ReLU/res) [+ per-wave GEMM], ONE node per 8-lane sub ------
// 1563 blocks x 32 nodes. Each lane owns one feature-octet of its sub's node.
// R6->R7: widen gather to 8 edges/iter (uint4 colp load, 8 uint4 rows in
// flight — 2x MLP, half the sequential chain), and hoist self-row/residual/BN
// loads above the loop (independent; compiler can't hoist past the break).
template <bool NSCALE, bool DOGEMM>
__global__ __launch_bounds__(256) void k_gather_fused(const __half* __restrict__ gin,
                                                      const unsigned short* __restrict__ colp,
                                                      const int* __restrict__ fill,
                                                      const float* __restrict__ b,
                                                      const float* __restrict__ gamma,
                                                      const float* __restrict__ beta,
                                                      const float* __restrict__ mean,
                                                      const float* __restrict__ var,
                                                      const float4* __restrict__ res4,
                                                      float4* __restrict__ h4,
                                                      const float* __restrict__ W,
                                                      __half* __restrict__ gout) {
    __shared__ float4 Wt[DOGEMM ? 16 * 65 : 1];
    __shared__ float4 hrow[DOGEMM ? 32 * 17 : 1];   // stride 17

    const int t = threadIdx.x;
    const int wv = t >> 6;
    const int lane = t & 63;
    const int hh8 = lane & 7;       // feature octet
    const int sub = lane >> 3;      // node slot within wave
    const int nl = wv * 8 + sub;    // local node 0..31
    const int n = blockIdx.x * 32 + nl;
    const bool nvalid = (n < N_NODES);

    if (DOGEMM) {
        const float4* Wv = (const float4*)W;
        for (int i = t; i < HID * 16; i += 256) {
            int h2 = i >> 4, k4 = i & 15;
            Wt[k4 * 65 + h2] = Wv[i];
        }
        __syncthreads();   // only block barrier: Wt visible before any use
    }

    const uint4* gv = (const uint4*)gin;  // row = 8 x uint4 (128 B)
    const int fl = nvalid ? fill[n] : 0;
    const int deg = fl < MAXDEG ? fl : MAXDEG;

    // independent loads issued BEFORE the gather chain: self row, residual
    const uint4 vself = gv[(size_t)(nvalid ? n : 0) * 8 + hh8];
    float4 r0 = make_float4(0.f, 0.f, 0.f, 0.f), r1 = r0;
    if (res4 != nullptr && nvalid) {
        r0 = res4[(size_t)n * 16 + hh8 * 2];
        r1 = res4[(size_t)n * 16 + hh8 * 2 + 1];
    }

    float a[8];
#pragma unroll
    for (int i = 0; i < 8; ++i) a[i] = 0.f;

    const uint4* cp8 = (const uint4*)(colp + (size_t)n * MAXDEG);  // 8 cols / 16 B

#pragma unroll 1
    for (int rb = 0; rb < MAXDEG; rb += 8) {
        if (!__any(rb < deg)) break;          // wave-uniform exit
        if (rb < deg) {                       // sub-uniform mask (8 lanes alike)
            uint4 cc = cp8[rb >> 3];          // 8 packed cols, one 16B load
            unsigned cw[4] = {cc.x, cc.y, cc.z, cc.w};
            int c[8]; float s[8]; uint4 v[8];
#pragma unroll
            for (int k = 0; k < 8; ++k) {
                bool pk = (rb + k) < deg;
                int col = (int)((cw[k >> 1] >> (16 * (k & 1))) & 0xFFFFu);
                c[k] = pk ? col : 0;
                if (NSCALE) s[k] = pk ? rsqrtf((float)fill[c[k]] + 1.0f) : 0.0f;
                else        s[k] = pk ? 1.0f : 0.0f;
            }
#pragma unroll
            for (int k = 0; k < 8; ++k) v[k] = gv[(size_t)c[k] * 8 + hh8];
#pragma unroll
            for (int k = 0; k < 8; ++k) acc8s(v[k], a, s[k]);
        }
    }

    const float di = rsqrtf((float)fl + 1.0f);
    if (nvalid) acc8s(vself, a, NSCALE ? di : 1.0f);  // self loop

    // BN fold (params long since in flight): o = a*di*SC + SH
    float o[8];
    {
        float4 b0 = ((const float4*)b)[hh8 * 2],     b1 = ((const float4*)b)[hh8 * 2 + 1];
        float4 g0 = ((const float4*)gamma)[hh8 * 2], g1 = ((const float4*)gamma)[hh8 * 2 + 1];
        float4 e0 = ((const float4*)beta)[hh8 * 2],  e1 = ((const float4*)beta)[hh8 * 2 + 1];
        float4 m0 = ((const float4*)mean)[hh8 * 2],  m1 = ((const float4*)mean)[hh8 * 2 + 1];
        float4 v0 = ((const float4*)var)[hh8 * 2],   v1 = ((const float4*)var)[hh8 * 2 + 1];
        float bb[8] = {b0.x, b0.y, b0.z, b0.w, b1.x, b1.y, b1.z, b1.w};
        float gg[8] = {g0.x, g0.y, g0.z, g0.w, g1.x, g1.y, g1.z, g1.w};
        float ee[8] = {e0.x, e0.y, e0.z, e0.w, e1.x, e1.y, e1.z, e1.w};
        float mm[8] = {m0.x, m0.y, m0.z, m0.w, m1.x, m1.y, m1.z, m1.w};
        float vv[8] = {v0.x, v0.y, v0.z, v0.w, v1.x, v1.y, v1.z, v1.w};
#pragma unroll
        for (int i = 0; i < 8; ++i) {
            float sc = gg[i] * rsqrtf(vv[i] + BN_EPS);
            float sh = (bb[i] - mm[i]) * sc + ee[i];
            o[i] = fmaxf(fmaf(a[i] * di, sc, sh), 0.f);
        }
    }

    o[0] += r0.x; o[1] += r0.y; o[2] += r0.z; o[3] += r0.w;
    o[4] += r1.x; o[5] += r1.y; o[6] += r1.z; o[7] += r1.w;

    float4 lo = make_float4(o[0], o[1], o[2], o[3]);
    float4 hi = make_float4(o[4], o[5], o[6], o[7]);
    if (nvalid) {
        h4[(size_t)n * 16 + hh8 * 2]     = lo;
        h4[(size_t)n * 16 + hh8 * 2 + 1] = hi;
    }

    if (DOGEMM) {
        // same-wave LDS write->read (rows wv*8..wv*8+7 only): in-order, no barrier
        hrow[nl * 17 + hh8 * 2]     = lo;
        hrow[nl * 17 + hh8 * 2 + 1] = hi;
        const int hh = lane;
        const int nb = blockIdx.x * 32 + wv * 8;
        float acc[8];
#pragma unroll
        for (int s8 = 0; s8 < 8; ++s8) acc[s8] = 0.f;
#pragma unroll 2
        for (int k4 = 0; k4 < 16; ++k4) {
            float4 w = Wt[k4 * 65 + hh];
#pragma unroll
            for (int s8 = 0; s8 < 8; ++s8) {
                float4 hv = hrow[(wv * 8 + s8) * 17 + k4];   // wave-broadcast (free)
                acc[s8] += hv.x * w.x + hv.y * w.y + hv.z * w.z + hv.w * w.w;
            }
        }
#pragma unroll
        for (int s8 = 0; s8 < 8; ++s8) {
            int ns = nb + s8;
            if (ns < N_NODES) {
                float dd = rsqrtf((float)fill[ns] + 1.0f);
                gout[(size_t)ns * HID + hh] = __float2half(acc[s8] * dd);
            }
        }
    }
}

// ---------------- pool + final linear: one 1024-thread block per graph ----------------
__device__ __forceinline__ int lowerb(const int* __restrict__ b, int val) {
    int lo = 0, hi = N_NODES;
    while (lo < hi) {
        int mid = (lo + hi) >> 1;
        if (b[mid] < val) lo = mid + 1; else hi = mid;
    }
    return lo;
}

__global__ __launch_bounds__(1024) void k_poolfinal(const float* __restrict__ h,
                                                    const int* __restrict__ batch,
                                                    const float* __restrict__ lin_w,
                                                    const float* __restrict__ lin_b,
                                                    float* __restrict__ out) {
    __shared__ float red[16][HID];
    int g = blockIdx.x;
    int w = threadIdx.x >> 6;
    int hh = threadIdx.x & 63;
    int start = lowerb(batch, g);
    int end = lowerb(batch, g + 1);
    int len = end - start;
    float acc = 0.f;
    for (int n = start + w; n < end; n += 16) acc += h[n * HID + hh];
    red[w][hh] = acc;
    __syncthreads();
    if (w == 0) {
        float s = 0.f;
#pragma unroll
        for (int i = 0; i < 16; ++i) s += red[i][hh];
        float c = fmaxf((float)len, 1.0f);
        float v = (s / c) * lin_w[hh];
#pragma unroll
        for (int off = 32; off > 0; off >>= 1) v += __shfl_down(v, off);
        if (hh == 0) out[g] = v + lin_b[0];
    }
}

extern "C" void kernel_launch(void* const* d_in, const int* in_sizes, int n_in,
                              void* d_out, int out_size, void* d_ws, size_t ws_size,
                              hipStream_t stream) {
    const float* x     = (const float*)d_in[0];
    const int*   ei    = (const int*)d_in[1];
    const int*   batch = (const int*)d_in[2];
    const float* W_in  = (const float*)d_in[3];
    const float* W1    = (const float*)d_in[4];
    const float* b1    = (const float*)d_in[5];
    const float* Ws    = (const float*)d_in[6];
    const float* bs_   = (const float*)d_in[7];
    const float* bn_g  = (const float*)d_in[8];
    const float* bn_b  = (const float*)d_in[9];
    const float* bn_m  = (const float*)d_in[10];
    const float* bn_v  = (const float*)d_in[11];
    const float* lin_w = (const float*)d_in[12];
    const float* lin_b = (const float*)d_in[13];
    float* out = (float*)d_out;

    char* q = (char*)d_ws;
    int*            fill = (int*)q;             q += (size_t)50048 * 4;
    unsigned short* colp = (unsigned short*)q;  q += (size_t)N_NODES * MAXDEG * 2;
    __half*         g16a = (__half*)q;          q += (size_t)N_NODES * HID * 2;
    __half*         g16b = (__half*)q;          q += (size_t)N_NODES * HID * 2;
    float*          h    = (float*)q;           q += (size_t)N_NODES * HID * 4;

    const int NB_N  = NB256(N_NODES);
    const int NB_GA = (N_NODES + 31) / 32;   // 1563
    float4* h4 = (float4*)h;

    // zero fill, then fused dual-GEMM (identity + layer-1) with deferred-store edge placement
    k_zero<<<NB_N, 256, 0, stream>>>(fill);
    k_gemmedge<<<GE_NB, 256, 0, stream>>>(ei, fill, colp, x, W_in, W1, h, g16a);

    // layer 1: gather (per-source dinv; g16a unscaled) + fused gemm for layer 2
    k_gather_fused<true, true><<<NB_GA, 256, 0, stream>>>(
        g16a, colp, fill, b1, bn_g, bn_b, bn_m, bn_v,
        (const float4*)h, h4, Ws + 0 * HID * HID, g16b);

    // layers 2-4: gather (pre-scaled g16) + fused gemm for next layer
    k_gather_fused<false, true><<<NB_GA, 256, 0, stream>>>(
        g16b, colp, fill, bs_ + 0 * HID,
        bn_g + 1 * HID, bn_b + 1 * HID, bn_m + 1 * HID, bn_v + 1 * HID,
        (const float4*)h, h4, Ws + 1 * HID * HID, g16a);

    k_gather_fused<false, true><<<NB_GA, 256, 0, stream>>>(
        g16a, colp, fill, bs_ + 1 * HID,
        bn_g + 2 * HID, bn_b + 2 * HID, bn_m + 2 * HID, bn_v + 2 * HID,
        (const float4*)h, h4, Ws + 2 * HID * HID, g16b);

    k_gather_fused<false, true><<<NB_GA, 256, 0, stream>>>(
        g16b, colp, fill, bs_ + 2 * HID,
        bn_g + 3 * HID, bn_b + 3 * HID, bn_m + 3 * HID, bn_v + 3 * HID,
        (const float4*)h, h4, Ws + 3 * HID * HID, g16a);

    // layer 5: gather only (no residual, no next gemm)
    k_gather_fused<false, false><<<NB_GA, 256, 0, stream>>>(
        g16a, colp, fill, bs_ + 3 * HID,
        bn_g + 4 * HID, bn_b + 4 * HID, bn_m + 4 * HID, bn_v + 4 * HID,
        nullptr, h4, nullptr, nullptr);

    // pool + final
    k_poolfinal<<<N_GRAPHS, 1024, 0, stream>>>(h, batch, lin_w, lin_b, out);
}

// Round 8
// 313.104 us; speedup vs baseline: 4.5999x; 1.0058x over previous
//
#include <hip/hip_runtime.h>
#include <hip/hip_fp16.h>

#define N_NODES 50000
#define N_FEAT  128
#define HID     64
#define N_EDGES 800000
#define N_GRAPHS 64
#define MAXDEG  64
#define BN_EPS  1e-5f
#define NB256(n) (((n) + 255) / 256)

// ---------------- zero fill counters ----------------
__global__ __launch_bounds__(256) void k_zero(int* fill) {
    int i = blockIdx.x * 256 + threadIdx.x;
    if (i < N_NODES) fill[i] = 0;
}

// ---------------- fused dual-GEMM with piggybacked edge placement ----------------
#define GE_NB 2500
__global__ __launch_bounds__(256) void k_gemmedge(const int* __restrict__ ei,
                                                  int* fill, unsigned short* __restrict__ colp,
                                                  const float* __restrict__ x,
                                                  const float* __restrict__ W_in,
                                                  const float* __restrict__ W1,
                                                  float* __restrict__ h,
                                                  __half* __restrict__ g16) {
    __shared__ float4 Wt[2][8 * 65];   // 8 k4-slices of both W, stride 65 (conflict-free)
    __shared__ float4 xs[20 * 32];     // 20 node rows of x
    const int bid = blockIdx.x;
    const int t = threadIdx.x;

    // edge slice: issue atomics now, consume results after the GEMM
    const int ebase = bid * 320;
    int s1 = ei[ebase + t];
    int d1 = ei[N_EDGES + ebase + t];
    int k1 = atomicAdd(&fill[d1], 1);
    int s2 = 0, d2 = 0, k2 = MAXDEG;
    if (t < 64) {
        s2 = ei[ebase + 256 + t];
        d2 = ei[N_EDGES + ebase + 256 + t];
        k2 = atomicAdd(&fill[d2], 1);
    }

    // W chunk 0 prefetch into registers (each thread owns 2 slots of each W)
    const float4* W0v = (const float4*)W_in;
    const float4* W1v = (const float4*)W1;
    const int h2a = t >> 3, k4a = t & 7;
    const int h2b = h2a + 32;                 // second slot: i = t + 256
    float4 w0a = W0v[h2a * 32 + k4a];
    float4 w1a = W1v[h2a * 32 + k4a];
    float4 w0b = W0v[h2b * 32 + k4a];
    float4 w1b = W1v[h2b * 32 + k4a];

    const int base = bid * 20;
    const float4* xv = (const float4*)(x + (long long)base * N_FEAT);
    for (int i = t; i < 20 * 32; i += 256) xs[i] = xv[i];

    const int hh = t & 63;
    const int ng = t >> 6;
    float4 a0[5], a1[5];
#pragma unroll
    for (int j = 0; j < 5; ++j) {
        a0[j] = make_float4(0.f, 0.f, 0.f, 0.f);
        a1[j] = make_float4(0.f, 0.f, 0.f, 0.f);
    }

    for (int c = 0; c < 32; c += 8) {
        __syncthreads();  // WAR on Wt (also orders xs staging before first MAC)
        Wt[0][k4a * 65 + h2a] = w0a;  Wt[1][k4a * 65 + h2a] = w1a;
        Wt[0][k4a * 65 + h2b] = w0b;  Wt[1][k4a * 65 + h2b] = w1b;
        if (c + 8 < 32) {   // prefetch next chunk; latency hides under compute
            w0a = W0v[h2a * 32 + c + 8 + k4a]; w1a = W1v[h2a * 32 + c + 8 + k4a];
            w0b = W0v[h2b * 32 + c + 8 + k4a]; w1b = W1v[h2b * 32 + c + 8 + k4a];
        }
        __syncthreads();
#pragma unroll
        for (int k4 = 0; k4 < 8; ++k4) {
            float4 w0 = Wt[0][k4 * 65 + hh];
            float4 w1 = Wt[1][k4 * 65 + hh];
#pragma unroll
            for (int j = 0; j < 5; ++j) {
                float4 xx = xs[(ng + 4 * j) * 32 + c + k4];   // wave-broadcast
                a0[j].x += w0.x * xx.x; a0[j].y += w0.y * xx.y;
                a0[j].z += w0.z * xx.z; a0[j].w += w0.w * xx.w;
                a1[j].x += w1.x * xx.x; a1[j].y += w1.y * xx.y;
                a1[j].z += w1.z * xx.z; a1[j].w += w1.w * xx.w;
            }
        }
    }
#pragma unroll
    for (int j = 0; j < 5; ++j) {
        int node = base + ng + 4 * j;
        h[node * HID + hh]   = a0[j].x + a0[j].y + a0[j].z + a0[j].w;
        g16[node * HID + hh] = __float2half(a1[j].x + a1[j].y + a1[j].z + a1[j].w);
    }

    // deferred stores: atomic results long since returned
    if (k1 < MAXDEG) colp[d1 * MAXDEG + k1] = (unsigned short)s1;
    if (k2 < MAXDEG) colp[d2 * MAXDEG + k2] = (unsigned short)s2;
}

// ---- fp16 row accumulate, scaled (FMA — same cost as plain add) ----
__device__ __forceinline__ void acc8s(const uint4 r, float* a, float s) {
    float2 f0 = __half22float2(*(const __half2*)&r.x);
    float2 f1 = __half22float2(*(const __half2*)&r.y);
    float2 f2 = __half22float2(*(const __half2*)&r.z);
    float2 f3 = __half22float2(*(const __half2*)&r.w);
    a[0] += s * f0.x; a[1] += s * f0.y; a[2] += s * f1.x; a[3] += s * f1.y;
    a[4] += s * f2.x; a[5] += s * f2.y; a[6] += s * f3.x; a[7] += s * f3.y;
}

// ---- gather pipeline helpers: 4-edge blocks, static indexing only ----
template <bool NSCALE>
__device__ __forceinline__ void unpack4(uint2 cc, int rb, int deg,
                                        const int* __restrict__ fill,
                                        int* c, float* s) {
    unsigned cw[2] = {cc.x, cc.y};
#pragma unroll
    for (int k = 0; k < 4; ++k) {
        bool pk = (rb + k) < deg;
        int col = (int)((cw[k >> 1] >> (16 * (k & 1))) & 0xFFFFu);
        c[k] = pk ? col : 0;                 // pad -> row 0 (finite data)
        if (NSCALE) s[k] = pk ? rsqrtf((float)fill[c[k]] + 1.0f) : 0.0f;
        else        s[k] = pk ? 1.0f : 0.0f;
    }
}
__device__ __forceinline__ void issue4(const uint4* __restrict__ gv,
                                       const int* c, int hh8, uint4* v) {
#pragma unroll
    for (int k = 0; k < 4; ++k) v[k] = gv[(size_t)c[k] * 8 + hh8];
}
__device__ __forceinline__ void accum4(const uint4* v, const float* s, float* a) {
#pragma unroll
    for (int k = 0; k < 4; ++k) acc8s(v[k], a, s[k]);
}

// ------ fused gather(+BN/ReLU/res) [+ per-wave GEMM], ONE node per 8-lane sub ------
// R7->R8: depth-2 software pipeline with NAMED ping-pong buffers (A/B) and a
// wave-uniform countable trip (shfl-max over subs) instead of the __any break
// (the break fenced all cross-iteration load hoisting -> per-block serialized
// L2/L3 latency). Rows(B) issue while rows(A) accumulate; colp prefetched 2
// blocks ahead (colp row = 16 uint2, in-row reads always in-bounds).
template <bool NSCALE, bool DOGEMM>
__global__ __launch_bounds__(256) void k_gather_fused(const __half* __restrict__ gin,
                                                      const unsigned short* __restrict__ colp,
                                                      const int* __restrict__ fill,
                                                      const float* __restrict__ b,
                                                      const float* __restrict__ gamma,
                                                      const float* __restrict__ beta,
                                                      const float* __restrict__ mean,
                                                      const float* __restrict__ var,
                                                      const float4* __restrict__ res4,
                                                      float4* __restrict__ h4,
                                                      const float* __restrict__ W,
                                                      __half* __restrict__ gout) {
    __shared__ float4 Wt[DOGEMM ? 16 * 65 : 1];
    __shared__ float4 hrow[DOGEMM ? 32 * 17 : 1];   // stride 17

    const int t = threadIdx.x;
    const int wv = t >> 6;
    const int lane = t & 63;
    const int hh8 = lane & 7;       // feature octet
    const int sub = lane >> 3;      // node slot within wave
    const int nl = wv * 8 + sub;    // local node 0..31
    const int n = blockIdx.x * 32 + nl;
    const bool nvalid = (n < N_NODES);

    if (DOGEMM) {
        const float4* Wv = (const float4*)W;
        for (int i = t; i < HID * 16; i += 256) {
            int h2 = i >> 4, k4 = i & 15;
            Wt[k4 * 65 + h2] = Wv[i];
        }
        __syncthreads();   // only block barrier: Wt visible before any use
    }

    const uint4* gv = (const uint4*)gin;  // row = 8 x uint4 (128 B)
    const int fl = nvalid ? fill[n] : 0;
    const int deg = fl < MAXDEG ? fl : MAXDEG;

    // independent loads issued BEFORE the gather chain: self row, residual
    const uint4 vself = gv[(size_t)(nvalid ? n : 0) * 8 + hh8];
    float4 r0 = make_float4(0.f, 0.f, 0.f, 0.f), r1 = r0;
    if (res4 != nullptr && nvalid) {
        r0 = res4[(size_t)n * 16 + hh8 * 2];
        r1 = res4[(size_t)n * 16 + hh8 * 2 + 1];
    }

    float a[8];
#pragma unroll
    for (int i = 0; i < 8; ++i) a[i] = 0.f;

    // wave-uniform block count: max over the 8 subs (lanes in a sub share deg)
    int nbw = (deg + 3) >> 2;
#pragma unroll
    for (int m = 8; m <= 32; m <<= 1) {
        int o = __shfl_xor(nbw, m);
        nbw = o > nbw ? o : nbw;
    }

    const uint2* cp4 = (const uint2*)(colp + (size_t)n * MAXDEG);  // 16 uint2/row

    uint2 ccA = cp4[0];
    uint2 ccB = cp4[1];
    int cA[4], cB[4]; float sA[4], sB[4]; uint4 vA[4], vB[4];
    unpack4<NSCALE>(ccA, 0, deg, fill, cA, sA);
    issue4(gv, cA, hh8, vA);

#pragma unroll 1
    for (int i = 0; i < nbw; i += 2) {
        unpack4<NSCALE>(ccB, (i + 1) * 4, deg, fill, cB, sB);
        issue4(gv, cB, hh8, vB);              // rows(i+1) in flight
        ccA = cp4[(i + 2) & 15];              // cols(i+2) in flight
        accum4(vA, sA, a);                    // consume rows(i)
        unpack4<NSCALE>(ccA, (i + 2) * 4, deg, fill, cA, sA);
        issue4(gv, cA, hh8, vA);              // rows(i+2) in flight
        ccB = cp4[(i + 3) & 15];              // cols(i+3) in flight
        accum4(vB, sB, a);                    // consume rows(i+1)
    }

    const float di = rsqrtf((float)fl + 1.0f);
    if (nvalid) acc8s(vself, a, NSCALE ? di : 1.0f);  // self loop

    // BN fold: o = a*di*SC + SH
    float o[8];
    {
        float4 b0 = ((const float4*)b)[hh8 * 2],     b1 = ((const float4*)b)[hh8 * 2 + 1];
        float4 g0 = ((const float4*)gamma)[hh8 * 2], g1 = ((const float4*)gamma)[hh8 * 2 + 1];
        float4 e0 = ((const float4*)beta)[hh8 * 2],  e1 = ((const float4*)beta)[hh8 * 2 + 1];
        float4 m0 = ((const float4*)mean)[hh8 * 2],  m1 = ((const float4*)mean)[hh8 * 2 + 1];
        float4 v0 = ((const float4*)var)[hh8 * 2],   v1 = ((const float4*)var)[hh8 * 2 + 1];
        float bb[8] = {b0.x, b0.y, b0.z, b0.w, b1.x, b1.y, b1.z, b1.w};
        float gg[8] = {g0.x, g0.y, g0.z, g0.w, g1.x, g1.y, g1.z, g1.w};
        float ee[8] = {e0.x, e0.y, e0.z, e0.w, e1.x, e1.y, e1.z, e1.w};
        float mm[8] = {m0.x, m0.y, m0.z, m0.w, m1.x, m1.y, m1.z, m1.w};
        float vv[8] = {v0.x, v0.y, v0.z, v0.w, v1.x, v1.y, v1.z, v1.w};
#pragma unroll
        for (int i = 0; i < 8; ++i) {
            float sc = gg[i] * rsqrtf(vv[i] + BN_EPS);
            float sh = (bb[i] - mm[i]) * sc + ee[i];
            o[i] = fmaxf(fmaf(a[i] * di, sc, sh), 0.f);
        }
    }

    o[0] += r0.x; o[1] += r0.y; o[2] += r0.z; o[3] += r0.w;
    o[4] += r1.x; o[5] += r1.y; o[6] += r1.z; o[7] += r1.w;

    float4 lo = make_float4(o[0], o[1], o[2], o[3]);
    float4 hi = make_float4(o[4], o[5], o[6], o[7]);
    if (nvalid) {
        h4[(size_t)n * 16 + hh8 * 2]     = lo;
        h4[(size_t)n * 16 + hh8 * 2 + 1] = hi;
    }

    if (DOGEMM) {
        // same-wave LDS write->read (rows wv*8..wv*8+7 only): in-order, no barrier
        hrow[nl * 17 + hh8 * 2]     = lo;
        hrow[nl * 17 + hh8 * 2 + 1] = hi;
        const int hh = lane;
        const int nb = blockIdx.x * 32 + wv * 8;
        float acc[8];
#pragma unroll
        for (int s8 = 0; s8 < 8; ++s8) acc[s8] = 0.f;
#pragma unroll 2
        for (int k4 = 0; k4 < 16; ++k4) {
            float4 w = Wt[k4 * 65 + hh];
#pragma unroll
            for (int s8 = 0; s8 < 8; ++s8) {
                float4 hv = hrow[(wv * 8 + s8) * 17 + k4];   // wave-broadcast (free)
                acc[s8] += hv.x * w.x + hv.y * w.y + hv.z * w.z + hv.w * w.w;
            }
        }
#pragma unroll
        for (int s8 = 0; s8 < 8; ++s8) {
            int ns = nb + s8;
            if (ns < N_NODES) {
                float dd = rsqrtf((float)fill[ns] + 1.0f);
                gout[(size_t)ns * HID + hh] = __float2half(acc[s8] * dd);
            }
        }
    }
}

// ---------------- pool + final linear: one 1024-thread block per graph ----------------
__device__ __forceinline__ int lowerb(const int* __restrict__ b, int val) {
    int lo = 0, hi = N_NODES;
    while (lo < hi) {
        int mid = (lo + hi) >> 1;
        if (b[mid] < val) lo = mid + 1; else hi = mid;
    }
    return lo;
}

__global__ __launch_bounds__(1024) void k_poolfinal(const float* __restrict__ h,
                                                    const int* __restrict__ batch,
                                                    const float* __restrict__ lin_w,
                                                    const float* __restrict__ lin_b,
                                                    float* __restrict__ out) {
    __shared__ float red[16][HID];
    int g = blockIdx.x;
    int w = threadIdx.x >> 6;
    int hh = threadIdx.x & 63;
    int start = lowerb(batch, g);
    int end = lowerb(batch, g + 1);
    int len = end - start;
    float acc = 0.f;
    for (int n = start + w; n < end; n += 16) acc += h[n * HID + hh];
    red[w][hh] = acc;
    __syncthreads();
    if (w == 0) {
        float s = 0.f;
#pragma unroll
        for (int i = 0; i < 16; ++i) s += red[i][hh];
        float c = fmaxf((float)len, 1.0f);
        float v = (s / c) * lin_w[hh];
#pragma unroll
        for (int off = 32; off > 0; off >>= 1) v += __shfl_down(v, off);
        if (hh == 0) out[g] = v + lin_b[0];
    }
}

extern "C" void kernel_launch(void* const* d_in, const int* in_sizes, int n_in,
                              void* d_out, int out_size, void* d_ws, size_t ws_size,
                              hipStream_t stream) {
    const float* x     = (const float*)d_in[0];
    const int*   ei    = (const int*)d_in[1];
    const int*   batch = (const int*)d_in[2];
    const float* W_in  = (const float*)d_in[3];
    const float* W1    = (const float*)d_in[4];
    const float* b1    = (const float*)d_in[5];
    const float* Ws    = (const float*)d_in[6];
    const float* bs_   = (const float*)d_in[7];
    const float* bn_g  = (const float*)d_in[8];
    const float* bn_b  = (const float*)d_in[9];
    const float* bn_m  = (const float*)d_in[10];
    const float* bn_v  = (const float*)d_in[11];
    const float* lin_w = (const float*)d_in[12];
    const float* lin_b = (const float*)d_in[13];
    float* out = (float*)d_out;

    char* q = (char*)d_ws;
    int*            fill = (int*)q;             q += (size_t)50048 * 4;
    unsigned short* colp = (unsigned short*)q;  q += (size_t)N_NODES * MAXDEG * 2;
    __half*         g16a = (__half*)q;          q += (size_t)N_NODES * HID * 2;
    __half*         g16b = (__half*)q;          q += (size_t)N_NODES * HID * 2;
    float*          h    = (float*)q;           q += (size_t)N_NODES * HID * 4;

    const int NB_N  = NB256(N_NODES);
    const int NB_GA = (N_NODES + 31) / 32;   // 1563
    float4* h4 = (float4*)h;

    // zero fill, then fused dual-GEMM (identity + layer-1) with deferred-store edge placement
    k_zero<<<NB_N, 256, 0, stream>>>(fill);
    k_gemmedge<<<GE_NB, 256, 0, stream>>>(ei, fill, colp, x, W_in, W1, h, g16a);

    // layer 1: gather (per-source dinv; g16a unscaled) + fused gemm for layer 2
    k_gather_fused<true, true><<<NB_GA, 256, 0, stream>>>(
        g16a, colp, fill, b1, bn_g, bn_b, bn_m, bn_v,
        (const float4*)h, h4, Ws + 0 * HID * HID, g16b);

    // layers 2-4: gather (pre-scaled g16) + fused gemm for next layer
    k_gather_fused<false, true><<<NB_GA, 256, 0, stream>>>(
        g16b, colp, fill, bs_ + 0 * HID,
        bn_g + 1 * HID, bn_b + 1 * HID, bn_m + 1 * HID, bn_v + 1 * HID,
        (const float4*)h, h4, Ws + 1 * HID * HID, g16a);

    k_gather_fused<false, true><<<NB_GA, 256, 0, stream>>>(
        g16a, colp, fill, bs_ + 1 * HID,
        bn_g + 2 * HID, bn_b + 2 * HID, bn_m + 2 * HID, bn_v + 2 * HID,
        (const float4*)h, h4, Ws + 2 * HID * HID, g16b);

    k_gather_fused<false, true><<<NB_GA, 256, 0, stream>>>(
        g16b, colp, fill, bs_ + 2 * HID,
        bn_g + 3 * HID, bn_b + 3 * HID, bn_m + 3 * HID, bn_v + 3 * HID,
        (const float4*)h, h4, Ws + 3 * HID * HID, g16a);

    // layer 5: gather only (no residual, no next gemm)
    k_gather_fused<false, false><<<NB_GA, 256, 0, stream>>>(
        g16a, colp, fill, bs_ + 3 * HID,
        bn_g + 4 * HID, bn_b + 4 * HID, bn_m + 4 * HID, bn_v + 4 * HID,
        nullptr, h4, nullptr, nullptr);

    // pool + final
    k_poolfinal<<<N_GRAPHS, 1024, 0, stream>>>(h, batch, lin_w, lin_b, out);
}

// Round 9
// 311.455 us; speedup vs baseline: 4.6243x; 1.0053x over previous
//
#include <hip/hip_runtime.h>
#include <hip/hip_fp16.h>

#define N_NODES 50000
#define N_FEAT  128
#define HID     64
#define N_EDGES 800000
#define N_GRAPHS 64
#define MAXDEG  64
#define BN_EPS  1e-5f
#define NB256(n) (((n) + 255) / 256)

// ---------------- zero fill counters ----------------
__global__ __launch_bounds__(256) void k_zero(int* fill) {
    int i = blockIdx.x * 256 + threadIdx.x;
    if (i < N_NODES) fill[i] = 0;
}

// ---------------- fused dual-GEMM with piggybacked edge placement ----------------
#define GE_NB 2500
__global__ __launch_bounds__(256) void k_gemmedge(const int* __restrict__ ei,
                                                  int* fill, unsigned short* __restrict__ colp,
                                                  const float* __restrict__ x,
                                                  const float* __restrict__ W_in,
                                                  const float* __restrict__ W1,
                                                  float* __restrict__ h,
                                                  __half* __restrict__ g16) {
    __shared__ float4 Wt[2][8 * 65];   // 8 k4-slices of both W, stride 65 (conflict-free)
    __shared__ float4 xs[20 * 32];     // 20 node rows of x
    const int bid = blockIdx.x;
    const int t = threadIdx.x;

    // edge slice: issue atomics now, consume results after the GEMM
    const int ebase = bid * 320;
    int s1 = ei[ebase + t];
    int d1 = ei[N_EDGES + ebase + t];
    int k1 = atomicAdd(&fill[d1], 1);
    int s2 = 0, d2 = 0, k2 = MAXDEG;
    if (t < 64) {
        s2 = ei[ebase + 256 + t];
        d2 = ei[N_EDGES + ebase + 256 + t];
        k2 = atomicAdd(&fill[d2], 1);
    }

    // W chunk 0 prefetch into registers (each thread owns 2 slots of each W)
    const float4* W0v = (const float4*)W_in;
    const float4* W1v = (const float4*)W1;
    const int h2a = t >> 3, k4a = t & 7;
    const int h2b = h2a + 32;                 // second slot: i = t + 256
    float4 w0a = W0v[h2a * 32 + k4a];
    float4 w1a = W1v[h2a * 32 + k4a];
    float4 w0b = W0v[h2b * 32 + k4a];
    float4 w1b = W1v[h2b * 32 + k4a];

    const int base = bid * 20;
    const float4* xv = (const float4*)(x + (long long)base * N_FEAT);
    for (int i = t; i < 20 * 32; i += 256) xs[i] = xv[i];

    const int hh = t & 63;
    const int ng = t >> 6;
    float4 a0[5], a1[5];
#pragma unroll
    for (int j = 0; j < 5; ++j) {
        a0[j] = make_float4(0.f, 0.f, 0.f, 0.f);
        a1[j] = make_float4(0.f, 0.f, 0.f, 0.f);
    }

    for (int c = 0; c < 32; c += 8) {
        __syncthreads();  // WAR on Wt (also orders xs staging before first MAC)
        Wt[0][k4a * 65 + h2a] = w0a;  Wt[1][k4a * 65 + h2a] = w1a;
        Wt[0][k4a * 65 + h2b] = w0b;  Wt[1][k4a * 65 + h2b] = w1b;
        if (c + 8 < 32) {   // prefetch next chunk; latency hides under compute
            w0a = W0v[h2a * 32 + c + 8 + k4a]; w1a = W1v[h2a * 32 + c + 8 + k4a];
            w0b = W0v[h2b * 32 + c + 8 + k4a]; w1b = W1v[h2b * 32 + c + 8 + k4a];
        }
        __syncthreads();
#pragma unroll
        for (int k4 = 0; k4 < 8; ++k4) {
            float4 w0 = Wt[0][k4 * 65 + hh];
            float4 w1 = Wt[1][k4 * 65 + hh];
#pragma unroll
            for (int j = 0; j < 5; ++j) {
                float4 xx = xs[(ng + 4 * j) * 32 + c + k4];   // wave-broadcast
                a0[j].x += w0.x * xx.x; a0[j].y += w0.y * xx.y;
                a0[j].z += w0.z * xx.z; a0[j].w += w0.w * xx.w;
                a1[j].x += w1.x * xx.x; a1[j].y += w1.y * xx.y;
                a1[j].z += w1.z * xx.z; a1[j].w += w1.w * xx.w;
            }
        }
    }
#pragma unroll
    for (int j = 0; j < 5; ++j) {
        int node = base + ng + 4 * j;
        h[node * HID + hh]   = a0[j].x + a0[j].y + a0[j].z + a0[j].w;
        g16[node * HID + hh] = __float2half(a1[j].x + a1[j].y + a1[j].z + a1[j].w);
    }

    // deferred stores: atomic results long since returned
    if (k1 < MAXDEG) colp[d1 * MAXDEG + k1] = (unsigned short)s1;
    if (k2 < MAXDEG) colp[d2 * MAXDEG + k2] = (unsigned short)s2;
}

// ---- fp16 row accumulate, scaled (FMA — same cost as plain add) ----
__device__ __forceinline__ void acc8s(const uint4 r, float* a, float s) {
    float2 f0 = __half22float2(*(const __half2*)&r.x);
    float2 f1 = __half22float2(*(const __half2*)&r.y);
    float2 f2 = __half22float2(*(const __half2*)&r.z);
    float2 f3 = __half22float2(*(const __half2*)&r.w);
    a[0] += s * f0.x; a[1] += s * f0.y; a[2] += s * f1.x; a[3] += s * f1.y;
    a[4] += s * f2.x; a[5] += s * f2.y; a[6] += s * f3.x; a[7] += s * f3.y;
}

// ------ fused gather(+BN/ReLU/res) [+ per-wave GEMM], ONE node per 8-lane sub ------
// R8->R9: occupancy is the lever (R6/R7/R8 ILP variants all flat ~50 µs; VGPR
// ~160+ -> only 2-3 waves/SIMD -> too few rows in flight per CU to cover the
// ~1-2K cyc random-access latency). Force <=128 VGPR via __launch_bounds__(256,4)
// (4 waves/SIMD, 2x in-flight rows/CU) and shrink the loop-crossing live set
// (self-row + residual loads moved AFTER the gather loop).
template <bool NSCALE, bool DOGEMM>
__global__ __launch_bounds__(256, 4) void k_gather_fused(const __half* __restrict__ gin,
                                                      const unsigned short* __restrict__ colp,
                                                      const int* __restrict__ fill,
                                                      const float* __restrict__ b,
                                                      const float* __restrict__ gamma,
                                                      const float* __restrict__ beta,
                                                      const float* __restrict__ mean,
                                                      const float* __restrict__ var,
                                                      const float4* __restrict__ res4,
                                                      float4* __restrict__ h4,
                                                      const float* __restrict__ W,
                                                      __half* __restrict__ gout) {
    __shared__ float4 Wt[DOGEMM ? 16 * 65 : 1];
    __shared__ float4 hrow[DOGEMM ? 32 * 17 : 1];   // stride 17

    const int t = threadIdx.x;
    const int wv = t >> 6;
    const int lane = t & 63;
    const int hh8 = lane & 7;       // feature octet
    const int sub = lane >> 3;      // node slot within wave
    const int nl = wv * 8 + sub;    // local node 0..31
    const int n = blockIdx.x * 32 + nl;
    const bool nvalid = (n < N_NODES);

    if (DOGEMM) {
        const float4* Wv = (const float4*)W;
        for (int i = t; i < HID * 16; i += 256) {
            int h2 = i >> 4, k4 = i & 15;
            Wt[k4 * 65 + h2] = Wv[i];
        }
        __syncthreads();   // only block barrier: Wt visible before any use
    }

    const uint4* gv = (const uint4*)gin;  // row = 8 x uint4 (128 B)
    const int fl = nvalid ? fill[n] : 0;
    const int deg = fl < MAXDEG ? fl : MAXDEG;

    float a[8];
#pragma unroll
    for (int i = 0; i < 8; ++i) a[i] = 0.f;

    const uint4* cp8 = (const uint4*)(colp + (size_t)n * MAXDEG);  // 8 cols / 16 B

#pragma unroll 1
    for (int rb = 0; rb < MAXDEG; rb += 8) {
        if (!__any(rb < deg)) break;          // wave-uniform exit
        if (rb < deg) {                       // sub-uniform mask (8 lanes alike)
            uint4 cc = cp8[rb >> 3];          // 8 packed cols, one 16B load
            unsigned cw[4] = {cc.x, cc.y, cc.z, cc.w};
            int c[8]; float s[8]; uint4 v[8];
#pragma unroll
            for (int k = 0; k < 8; ++k) {
                bool pk = (rb + k) < deg;
                int col = (int)((cw[k >> 1] >> (16 * (k & 1))) & 0xFFFFu);
                c[k] = pk ? col : 0;
                if (NSCALE) s[k] = pk ? rsqrtf((float)fill[c[k]] + 1.0f) : 0.0f;
                else        s[k] = pk ? 1.0f : 0.0f;
            }
#pragma unroll
            for (int k = 0; k < 8; ++k) v[k] = gv[(size_t)c[k] * 8 + hh8];
#pragma unroll
            for (int k = 0; k < 8; ++k) acc8s(v[k], a, s[k]);
        }
    }

    const float di = rsqrtf((float)fl + 1.0f);
    if (nvalid) acc8s(gv[(size_t)n * 8 + hh8], a, NSCALE ? di : 1.0f);  // self loop

    // BN fold (post-loop; params from L2): o = a*di*SC + SH
    float o[8];
    {
        float4 b0 = ((const float4*)b)[hh8 * 2],     b1 = ((const float4*)b)[hh8 * 2 + 1];
        float4 g0 = ((const float4*)gamma)[hh8 * 2], g1 = ((const float4*)gamma)[hh8 * 2 + 1];
        float4 e0 = ((const float4*)beta)[hh8 * 2],  e1 = ((const float4*)beta)[hh8 * 2 + 1];
        float4 m0 = ((const float4*)mean)[hh8 * 2],  m1 = ((const float4*)mean)[hh8 * 2 + 1];
        float4 v0 = ((const float4*)var)[hh8 * 2],   v1 = ((const float4*)var)[hh8 * 2 + 1];
        float bb[8] = {b0.x, b0.y, b0.z, b0.w, b1.x, b1.y, b1.z, b1.w};
        float gg[8] = {g0.x, g0.y, g0.z, g0.w, g1.x, g1.y, g1.z, g1.w};
        float ee[8] = {e0.x, e0.y, e0.z, e0.w, e1.x, e1.y, e1.z, e1.w};
        float mm[8] = {m0.x, m0.y, m0.z, m0.w, m1.x, m1.y, m1.z, m1.w};
        float vv[8] = {v0.x, v0.y, v0.z, v0.w, v1.x, v1.y, v1.z, v1.w};
#pragma unroll
        for (int i = 0; i < 8; ++i) {
            float sc = gg[i] * rsqrtf(vv[i] + BN_EPS);
            float sh = (bb[i] - mm[i]) * sc + ee[i];
            o[i] = fmaxf(fmaf(a[i] * di, sc, sh), 0.f);
        }
    }

    // residual (loaded post-loop: L2-resident, consumed immediately)
    if (res4 != nullptr && nvalid) {
        float4 r0 = res4[(size_t)n * 16 + hh8 * 2];
        float4 r1 = res4[(size_t)n * 16 + hh8 * 2 + 1];
        o[0] += r0.x; o[1] += r0.y; o[2] += r0.z; o[3] += r0.w;
        o[4] += r1.x; o[5] += r1.y; o[6] += r1.z; o[7] += r1.w;
    }

    float4 lo = make_float4(o[0], o[1], o[2], o[3]);
    float4 hi = make_float4(o[4], o[5], o[6], o[7]);
    if (nvalid) {
        h4[(size_t)n * 16 + hh8 * 2]     = lo;
        h4[(size_t)n * 16 + hh8 * 2 + 1] = hi;
    }

    if (DOGEMM) {
        // same-wave LDS write->read (rows wv*8..wv*8+7 only): in-order, no barrier
        hrow[nl * 17 + hh8 * 2]     = lo;
        hrow[nl * 17 + hh8 * 2 + 1] = hi;
        const int hh = lane;
        const int nb = blockIdx.x * 32 + wv * 8;
        float acc[8];
#pragma unroll
        for (int s8 = 0; s8 < 8; ++s8) acc[s8] = 0.f;
#pragma unroll 2
        for (int k4 = 0; k4 < 16; ++k4) {
            float4 w = Wt[k4 * 65 + hh];
#pragma unroll
            for (int s8 = 0; s8 < 8; ++s8) {
                float4 hv = hrow[(wv * 8 + s8) * 17 + k4];   // wave-broadcast (free)
                acc[s8] += hv.x * w.x + hv.y * w.y + hv.z * w.z + hv.w * w.w;
            }
        }
#pragma unroll
        for (int s8 = 0; s8 < 8; ++s8) {
            int ns = nb + s8;
            if (ns < N_NODES) {
                float dd = rsqrtf((float)fill[ns] + 1.0f);
                gout[(size_t)ns * HID + hh] = __float2half(acc[s8] * dd);
            }
        }
    }
}

// ---------------- pool + final linear: one 1024-thread block per graph ----------------
__device__ __forceinline__ int lowerb(const int* __restrict__ b, int val) {
    int lo = 0, hi = N_NODES;
    while (lo < hi) {
        int mid = (lo + hi) >> 1;
        if (b[mid] < val) lo = mid + 1; else hi = mid;
    }
    return lo;
}

__global__ __launch_bounds__(1024) void k_poolfinal(const float* __restrict__ h,
                                                    const int* __restrict__ batch,
                                                    const float* __restrict__ lin_w,
                                                    const float* __restrict__ lin_b,
                                                    float* __restrict__ out) {
    __shared__ float red[16][HID];
    int g = blockIdx.x;
    int w = threadIdx.x >> 6;
    int hh = threadIdx.x & 63;
    int start = lowerb(batch, g);
    int end = lowerb(batch, g + 1);
    int len = end - start;
    float acc = 0.f;
    for (int n = start + w; n < end; n += 16) acc += h[n * HID + hh];
    red[w][hh] = acc;
    __syncthreads();
    if (w == 0) {
        float s = 0.f;
#pragma unroll
        for (int i = 0; i < 16; ++i) s += red[i][hh];
        float c = fmaxf((float)len, 1.0f);
        float v = (s / c) * lin_w[hh];
#pragma unroll
        for (int off = 32; off > 0; off >>= 1) v += __shfl_down(v, off);
        if (hh == 0) out[g] = v + lin_b[0];
    }
}

extern "C" void kernel_launch(void* const* d_in, const int* in_sizes, int n_in,
                              void* d_out, int out_size, void* d_ws, size_t ws_size,
                              hipStream_t stream) {
    const float* x     = (const float*)d_in[0];
    const int*   ei    = (const int*)d_in[1];
    const int*   batch = (const int*)d_in[2];
    const float* W_in  = (const float*)d_in[3];
    const float* W1    = (const float*)d_in[4];
    const float* b1    = (const float*)d_in[5];
    const float* Ws    = (const float*)d_in[6];
    const float* bs_   = (const float*)d_in[7];
    const float* bn_g  = (const float*)d_in[8];
    const float* bn_b  = (const float*)d_in[9];
    const float* bn_m  = (const float*)d_in[10];
    const float* bn_v  = (const float*)d_in[11];
    const float* lin_w = (const float*)d_in[12];
    const float* lin_b = (const float*)d_in[13];
    float* out = (float*)d_out;

    char* q = (char*)d_ws;
    int*            fill = (int*)q;             q += (size_t)50048 * 4;
    unsigned short* colp = (unsigned short*)q;  q += (size_t)N_NODES * MAXDEG * 2;
    __half*         g16a = (__half*)q;          q += (size_t)N_NODES * HID * 2;
    __half*         g16b = (__half*)q;          q += (size_t)N_NODES * HID * 2;
    float*          h    = (float*)q;           q += (size_t)N_NODES * HID * 4;

    const int NB_N  = NB256(N_NODES);
    const int NB_GA = (N_NODES + 31) / 32;   // 1563
    float4* h4 = (float4*)h;

    // zero fill, then fused dual-GEMM (identity + layer-1) with deferred-store edge placement
    k_zero<<<NB_N, 256, 0, stream>>>(fill);
    k_gemmedge<<<GE_NB, 256, 0, stream>>>(ei, fill, colp, x, W_in, W1, h, g16a);

    // layer 1: gather (per-source dinv; g16a unscaled) + fused gemm for layer 2
    k_gather_fused<true, true><<<NB_GA, 256, 0, stream>>>(
        g16a, colp, fill, b1, bn_g, bn_b, bn_m, bn_v,
        (const float4*)h, h4, Ws + 0 * HID * HID, g16b);

    // layers 2-4: gather (pre-scaled g16) + fused gemm for next layer
    k_gather_fused<false, true><<<NB_GA, 256, 0, stream>>>(
        g16b, colp, fill, bs_ + 0 * HID,
        bn_g + 1 * HID, bn_b + 1 * HID, bn_m + 1 * HID, bn_v + 1 * HID,
        (const float4*)h, h4, Ws + 1 * HID * HID, g16a);

    k_gather_fused<false, true><<<NB_GA, 256, 0, stream>>>(
        g16a, colp, fill, bs_ + 1 * HID,
        bn_g + 2 * HID, bn_b + 2 * HID, bn_m + 2 * HID, bn_v + 2 * HID,
        (const float4*)h, h4, Ws + 2 * HID * HID, g16b);

    k_gather_fused<false, true><<<NB_GA, 256, 0, stream>>>(
        g16b, colp, fill, bs_ + 2 * HID,
        bn_g + 3 * HID, bn_b + 3 * HID, bn_m + 3 * HID, bn_v + 3 * HID,
        (const float4*)h, h4, Ws + 3 * HID * HID, g16a);

    // layer 5: gather only (no residual, no next gemm)
    k_gather_fused<false, false><<<NB_GA, 256, 0, stream>>>(
        g16a, colp, fill, bs_ + 3 * HID,
        bn_g + 4 * HID, bn_b + 4 * HID, bn_m + 4 * HID, bn_v + 4 * HID,
        nullptr, h4, nullptr, nullptr);

    // pool + final
    k_poolfinal<<<N_GRAPHS, 1024, 0, stream>>>(h, batch, lin_w, lin_b, out);
}